// Round 7
// baseline (356.883 us; speedup 1.0000x reference)
//
#include <hip/hip_runtime.h>
#include <hip/hip_bf16.h>

#define NNODES 50000
#define NEDGES 200000
#define DD 128
#define LN_EPS 1e-5f
#define NTH 256

typedef __attribute__((ext_vector_type(8))) short bf16x8;
typedef __attribute__((ext_vector_type(4))) float f32x4;
typedef __attribute__((ext_vector_type(16))) float f32x16;

template<int N> struct ic { static constexpr int value = N; };

__device__ __forceinline__ unsigned short bfr(float f) {
    union { __hip_bfloat16 b; unsigned short u; } v;
    v.b = __float2bfloat16(f);
    return v.u;
}

// ---------------------------------------------------------------------------
// Weight image, coalesced-frag layout. Per k32 chunk c (8 KB):
//   byte = c*8192 + nt*2048 + ks*512 + n32*16
//   content: Wt[n = nt*32+n32][k = c*32 + ks*8 + e], e=0..7 (bf16)
// A-frag load (fixed nt, ks = kh*2+hi): lanes cover two contiguous 512 B
// blocks -> 2 transactions per instruction, L2-resident.
// ---------------------------------------------------------------------------
__global__ void build_wimg(const float* __restrict__ We1, const float* __restrict__ We2,
                           const float* __restrict__ We3, const float* __restrict__ Wn1,
                           const float* __restrict__ Wn2, const float* __restrict__ Wn3,
                           char* __restrict__ img_e, char* __restrict__ img_n) {
    int tid = blockIdx.x * NTH + threadIdx.x;
    const float* W; char* dst; int q;
    if      (tid <  6144) { W = We1; dst = img_e;             q = tid;         }
    else if (tid <  8192) { W = We2; dst = img_e + 12 * 8192; q = tid - 6144;  }
    else if (tid < 10240) { W = We3; dst = img_e + 16 * 8192; q = tid - 8192;  }
    else if (tid < 14336) { W = Wn1; dst = img_n;             q = tid - 10240; }
    else if (tid < 16384) { W = Wn2; dst = img_n + 8 * 8192;  q = tid - 14336; }
    else if (tid < 18432) { W = Wn3; dst = img_n + 12 * 8192; q = tid - 16384; }
    else return;
    int c = q >> 9, rem = q & 511;
    int nt = rem >> 7, r2 = rem & 127, ks = r2 >> 5, n32 = r2 & 31;
    int n = nt * 32 + n32;
    int k0 = c * 32 + ks * 8;
    unsigned short o[8];
    #pragma unroll
    for (int e = 0; e < 8; ++e)
        o[e] = bfr(W[(size_t)(k0 + e) * DD + n]);
    uint4 val;
    val.x = (unsigned)o[0] | ((unsigned)o[1] << 16);
    val.y = (unsigned)o[2] | ((unsigned)o[3] << 16);
    val.z = (unsigned)o[4] | ((unsigned)o[5] << 16);
    val.w = (unsigned)o[6] | ((unsigned)o[7] << 16);
    *(uint4*)(dst + (size_t)c * 8192 + nt * 2048 + ks * 512 + n32 * 16) = val;
}

// ---------------------------------------------------------------------------
// CSR build: histogram -> single-block scan -> fill
// ---------------------------------------------------------------------------
__global__ void csr_histo(const int* __restrict__ recv, int* __restrict__ cnt) {
    int e = blockIdx.x * NTH + threadIdx.x;
    if (e < NEDGES) atomicAdd(&cnt[recv[e]], 1);
}

__global__ __launch_bounds__(1024)
void csr_scan(const int* __restrict__ cnt, int* __restrict__ off, int* __restrict__ cursor) {
    __shared__ int part[1024];
    const int t = threadIdx.x;
    const int CH = (NNODES + 1023) / 1024;
    const int base = t * CH;
    int s = 0;
    for (int i = 0; i < CH; ++i) {
        int idx = base + i;
        if (idx < NNODES) s += cnt[idx];
    }
    part[t] = s;
    __syncthreads();
    for (int d = 1; d < 1024; d <<= 1) {
        int v = (t >= d) ? part[t - d] : 0;
        __syncthreads();
        part[t] += v;
        __syncthreads();
    }
    int run = (t == 0) ? 0 : part[t - 1];
    for (int i = 0; i < CH; ++i) {
        int idx = base + i;
        if (idx < NNODES) {
            off[idx] = run; cursor[idx] = run;
            run += cnt[idx];
        }
    }
    if (t == 1023) off[NNODES] = NEDGES;
}

__global__ void csr_fill(const int* __restrict__ recv, int* __restrict__ cursor,
                         int* __restrict__ elist) {
    int e = blockIdx.x * NTH + threadIdx.x;
    if (e < NEDGES) {
        int p = atomicAdd(&cursor[recv[e]], 1);
        elist[p] = e;
    }
}

// ---------------------------------------------------------------------------
// Aggregate (bf16): aggb[n] = sum over receiver-edges of ybuf[e]
// ybuf rows are 256 B bf16; one wave per node, lane holds 2 columns (4 B).
// ---------------------------------------------------------------------------
__global__ __launch_bounds__(NTH)
void aggregate(const unsigned* __restrict__ ybuf,
               const int* __restrict__ off, const int* __restrict__ elist,
               unsigned* __restrict__ aggb) {
    const int n = blockIdx.x * 4 + (threadIdx.x >> 6);
    const int l = threadIdx.x & 63;
    if (n >= NNODES) return;
    const int j0 = off[n], j1 = off[n + 1];
    float ax = 0.f, ay = 0.f, bx = 0.f, by = 0.f;
    int j = j0;
    for (; j + 1 < j1; j += 2) {
        unsigned v0 = ybuf[(size_t)elist[j] * 64 + l];
        unsigned v1 = ybuf[(size_t)elist[j + 1] * 64 + l];
        ax += __uint_as_float(v0 << 16);
        ay += __uint_as_float(v0 & 0xffff0000u);
        bx += __uint_as_float(v1 << 16);
        by += __uint_as_float(v1 & 0xffff0000u);
    }
    if (j < j1) {
        unsigned v = ybuf[(size_t)elist[j] * 64 + l];
        ax += __uint_as_float(v << 16);
        ay += __uint_as_float(v & 0xffff0000u);
    }
    float sx = ax + bx, sy = ay + by;
    aggb[(size_t)n * 64 + l] = (unsigned)bfr(sx) | ((unsigned)bfr(sy) << 16);
}

// ---------------------------------------------------------------------------
// Fused MLP, 32x32x16 MFMA, barrier-free.  MODE 0 = edge, MODE 1 = node.
// 4 waves x 32 rows = 128 rows/block; waves fully independent (no LDS-W).
// A: direct from coalesced weight image (L2-hot), half-chunk rotation (2 slots).
// B: per-lane row gathers, 2-chunk rotation; node c>=4 reads bf16 agg direct.
// H1/H2: wave-private swizzled LDS (8 KB/wave), no barriers anywhere.
// ---------------------------------------------------------------------------
template<int MODE>
__global__ __launch_bounds__(NTH, 3)
void mgn_mfma(const float* __restrict__ nodef, const float* __restrict__ edgef,
              const int* __restrict__ senders, const int* __restrict__ receivers,
              const char* __restrict__ img,
              const float* __restrict__ b1, const float* __restrict__ b2,
              const float* __restrict__ b3,
              const float* __restrict__ gamma, const float* __restrict__ beta,
              const unsigned* __restrict__ aggb, unsigned* __restrict__ ybuf,
              float* __restrict__ outp)
{
    __shared__ char Hb[4 * 8192];     // per-wave 32 rows x 128 k bf16, swizzled

    const int t  = threadIdx.x;
    const int w  = t >> 6;
    const int l  = t & 63;
    const int ln = l & 31;            // A: weight col n32 | B/C: X row m32
    const int hi = l >> 5;
    const int row0 = blockIdx.x * 128;
    const int gm = row0 + w * 32 + ln;
    constexpr int NROWS = (MODE == 0) ? NEDGES : NNODES;
    constexpr int NK1   = (MODE == 0) ? 12 : 8;
    constexpr int NCH   = NK1 + 8;
    const int gmc = gm < NROWS ? gm : NROWS - 1;
    const int sxH = ln & 15;          // Hb slot swizzle

    int srow = 0, rrow = 0;
    if (MODE == 0) { srow = senders[gmc]; rrow = receivers[gmc]; }

    const f32x16 fz = {0.f,0.f,0.f,0.f,0.f,0.f,0.f,0.f,
                       0.f,0.f,0.f,0.f,0.f,0.f,0.f,0.f};
    f32x16 acc[4];
    #pragma unroll
    for (int nt = 0; nt < 4; ++nt) acc[nt] = fz;

    bf16x8 aslot[2][4];   // half-chunk A rotation
    f32x4  bslot[2][4];   // chunk B rotation (fp32 or raw bf16 bits)

    // ---- A half-chunk load: h = c*2 + kh; 4 ntile frags, contiguous 512 B ----
    auto loadA = [&](int h, bf16x8* dst) {
        const char* p = img + (size_t)(h >> 1) * 8192
                      + (size_t)(((h & 1) * 2 + hi) * 512) + ln * 16;
        #pragma unroll
        for (int nt = 0; nt < 4; ++nt)
            dst[nt] = *(const bf16x8*)(p + nt * 2048);
    };

    // ---- B gather for chunk c ----
    auto loadB = [&](auto CC, f32x4* dst) {
        constexpr int c = decltype(CC)::value;
        if constexpr (MODE == 1 && c >= 4) {
            const char* p = (const char*)aggb + (size_t)gmc * 256 + (c & 3) * 64 + hi * 16;
            dst[0] = *(const f32x4*)p;          // kh0, raw bf16x8 bits
            dst[2] = *(const f32x4*)(p + 32);   // kh1
        } else {
            const float* base;
            if constexpr (MODE == 0) {
                base = (c < 4) ? nodef + (size_t)srow * DD
                     : (c < 8) ? nodef + (size_t)rrow * DD
                               : edgef + (size_t)gmc * DD;
            } else {
                base = nodef + (size_t)gmc * DD;
            }
            const float* p = base + (c & 3) * 32 + hi * 8;
            dst[0] = *(const f32x4*)p;
            dst[1] = *(const f32x4*)(p + 4);
            dst[2] = *(const f32x4*)(p + 16);
            dst[3] = *(const f32x4*)(p + 20);
        }
    };

    auto cvtB = [&](const f32x4* br) {
        bf16x8 r;
        #pragma unroll
        for (int i = 0; i < 4; ++i) r[i]     = (short)bfr(br[0][i]);
        #pragma unroll
        for (int i = 0; i < 4; ++i) r[4 + i] = (short)bfr(br[1][i]);
        return r;
    };

    // ---- H read: slot sk = ks*4 + kh*2 + hi, swizzled ----
    auto loadBH = [&](int ks, int kh) {
        const char* p = Hb + w * 8192 + ln * 256
                      + (((ks * 4 + kh * 2 + hi) ^ sxH) << 4);
        return *(const bf16x8*)p;
    };

    auto getB = [&](auto CC, int kh) -> bf16x8 {
        constexpr int c = decltype(CC)::value;
        if constexpr (c >= NK1) {
            return loadBH((c - NK1) & 3, kh);
        } else if constexpr (MODE == 1 && c >= 4) {
            union { f32x4 f; bf16x8 h; } u;
            u.f = bslot[c & 1][kh * 2];
            return u.h;
        } else {
            return cvtB(&bslot[c & 1][kh * 2]);
        }
    };

    // ---- bias + relu -> Hb (quad writes, 8 B), reset acc ----
    auto epiH = [&](const float* bias) {
        #pragma unroll
        for (int nt = 0; nt < 4; ++nt) {
            #pragma unroll
            for (int rq = 0; rq < 4; ++rq) {
                f32x4 bv = *(const f32x4*)(bias + nt * 32 + rq * 8 + hi * 4);
                unsigned short h[4];
                #pragma unroll
                for (int j = 0; j < 4; ++j)
                    h[j] = bfr(fmaxf(acc[nt][rq * 4 + j] + bv[j], 0.f));
                char* p = Hb + w * 8192 + ln * 256
                        + (((nt * 4 + rq) ^ sxH) << 4) + hi * 8;
                unsigned lo = (unsigned)h[0] | ((unsigned)h[1] << 16);
                unsigned hx = (unsigned)h[2] | ((unsigned)h[3] << 16);
                *(unsigned long long*)p =
                    (unsigned long long)lo | ((unsigned long long)hx << 32);
            }
            acc[nt] = fz;
        }
    };

    // ---- one k32 chunk ----
    auto chunkfn = [&](auto CC) {
        constexpr int c = decltype(CC)::value;
        constexpr int h0 = 2 * c, h1 = 2 * c + 1;
        // half kh=0: prefetch A(h1), consume aslot[h0]
        loadA(h1, aslot[h1 & 1]);
        {
            bf16x8 b0 = getB(CC, 0);
            #pragma unroll
            for (int nt = 0; nt < 4; ++nt)
                acc[nt] = __builtin_amdgcn_mfma_f32_32x32x16_bf16(
                    aslot[h0 & 1][nt], b0, acc[nt], 0, 0, 0);
        }
        // half kh=1: prefetch A(h1+1), consume aslot[h1]
        if constexpr (h1 + 1 < 2 * NCH) loadA(h1 + 1, aslot[(h1 + 1) & 1]);
        {
            bf16x8 b1 = getB(CC, 1);
            #pragma unroll
            for (int nt = 0; nt < 4; ++nt)
                acc[nt] = __builtin_amdgcn_mfma_f32_32x32x16_bf16(
                    aslot[h1 & 1][nt], b1, acc[nt], 0, 0, 0);
        }
        // refill freed B slot (2-chunk lead)
        if constexpr (c + 2 < NK1) loadB(ic<c + 2>{}, bslot[c & 1]);
    };

    // prologue
    loadB(ic<0>{}, bslot[0]);
    loadB(ic<1>{}, bslot[1]);
    loadA(0, aslot[0]);

#define CH(C)                                                                \
    if constexpr ((C) < NCH) {                                               \
        chunkfn(ic<(C)>{});                                                  \
        if constexpr ((C) == NK1 - 1) epiH(b1);                              \
        if constexpr ((C) == NK1 + 3) epiH(b2);                              \
    }
    CH(0)  CH(1)  CH(2)  CH(3)  CH(4)  CH(5)  CH(6)  CH(7)
    CH(8)  CH(9)  CH(10) CH(11) CH(12) CH(13) CH(14) CH(15)
    CH(16) CH(17) CH(18) CH(19)
#undef CH

    // ================= bias3 + LayerNorm + residual (+ ybuf) =================
    float vsum = 0.f, vsq = 0.f;
    #pragma unroll
    for (int nt = 0; nt < 4; ++nt) {
        #pragma unroll
        for (int rq = 0; rq < 4; ++rq) {
            f32x4 bv = *(const f32x4*)(b3 + nt * 32 + rq * 8 + hi * 4);
            #pragma unroll
            for (int j = 0; j < 4; ++j) {
                float v = acc[nt][rq * 4 + j] + bv[j];
                acc[nt][rq * 4 + j] = v;
                vsum += v; vsq += v * v;
            }
        }
    }
    vsum += __shfl_xor(vsum, 32);
    vsq  += __shfl_xor(vsq, 32);
    const float mu = vsum * (1.f / DD);
    const float rs = rsqrtf(vsq * (1.f / DD) - mu * mu + LN_EPS);

    if (gm < NROWS) {
        const float* resid = ((MODE == 0) ? edgef : nodef) + (size_t)gm * DD;
        #pragma unroll
        for (int nt = 0; nt < 4; ++nt) {
            #pragma unroll
            for (int rq = 0; rq < 4; ++rq) {
                const int n0 = nt * 32 + rq * 8 + hi * 4;
                f32x4 gv = *(const f32x4*)(gamma + n0);
                f32x4 bv = *(const f32x4*)(beta + n0);
                f32x4 rv = *(const f32x4*)(resid + n0);
                float y[4];
                f32x4 o;
                #pragma unroll
                for (int j = 0; j < 4; ++j) {
                    y[j] = (acc[nt][rq * 4 + j] - mu) * rs * gv[j] + bv[j];
                    o[j] = y[j] + rv[j];
                }
                *(f32x4*)(outp + (size_t)gm * DD + n0) = o;
                if (MODE == 0) {
                    unsigned lo = (unsigned)bfr(y[0]) | ((unsigned)bfr(y[1]) << 16);
                    unsigned hx = (unsigned)bfr(y[2]) | ((unsigned)bfr(y[3]) << 16);
                    *(unsigned long long*)((char*)ybuf + (size_t)gm * 256 + n0 * 2) =
                        (unsigned long long)lo | ((unsigned long long)hx << 32);
                }
            }
        }
    }
}

extern "C" void kernel_launch(void* const* d_in, const int* in_sizes, int n_in,
                              void* d_out, int out_size, void* d_ws, size_t ws_size,
                              hipStream_t stream) {
    const float* nodef = (const float*)d_in[0];
    const float* edgef = (const float*)d_in[1];
    const int* senders   = (const int*)d_in[2];
    const int* receivers = (const int*)d_in[3];
    const float* We1 = (const float*)d_in[4],  *be1 = (const float*)d_in[5];
    const float* We2 = (const float*)d_in[6],  *be2 = (const float*)d_in[7];
    const float* We3 = (const float*)d_in[8],  *be3 = (const float*)d_in[9];
    const float* ge  = (const float*)d_in[10], *bege = (const float*)d_in[11];
    const float* Wn1 = (const float*)d_in[12], *bn1 = (const float*)d_in[13];
    const float* Wn2 = (const float*)d_in[14], *bn2 = (const float*)d_in[15];
    const float* Wn3 = (const float*)d_in[16], *bn3 = (const float*)d_in[17];
    const float* gn  = (const float*)d_in[18], *begn = (const float*)d_in[19];

    float* out_node = (float*)d_out;
    float* out_edge = (float*)d_out + (size_t)NNODES * DD;

    char* ws = (char*)d_ws;
    size_t o = 0;
    unsigned* aggb = (unsigned*)(ws + o); o += (size_t)NNODES * 256;   // 12.8 MB bf16
    unsigned* ybuf = (unsigned*)(ws + o); o += (size_t)NEDGES * 256;   // 51.2 MB bf16
    char* img_e = ws + o;           o += 20 * 8192;                    // 160 KB
    char* img_n = ws + o;           o += 16 * 8192;                    // 128 KB
    int* cnt    = (int*)(ws + o);   o += NNODES * 4;
    int* cursor = (int*)(ws + o);   o += NNODES * 4;
    int* off    = (int*)(ws + o);   o += (NNODES + 4) * 4;
    int* elist  = (int*)(ws + o);   o += NEDGES * 4;

    hipMemsetAsync(cnt, 0, NNODES * 4, stream);
    build_wimg<<<72, NTH, 0, stream>>>(We1, We2, We3, Wn1, Wn2, Wn3, img_e, img_n);

    const int egrid = (NEDGES + NTH - 1) / NTH;
    csr_histo<<<egrid, NTH, 0, stream>>>(receivers, cnt);
    csr_scan<<<1, 1024, 0, stream>>>(cnt, off, cursor);
    csr_fill<<<egrid, NTH, 0, stream>>>(receivers, cursor, elist);

    mgn_mfma<0><<<dim3((NEDGES + 127) / 128), dim3(NTH), 0, stream>>>(
        nodef, edgef, senders, receivers, img_e,
        be1, be2, be3, ge, bege, aggb, ybuf, out_edge);

    aggregate<<<(NNODES + 3) / 4, NTH, 0, stream>>>(ybuf, off, elist, aggb);

    mgn_mfma<1><<<dim3((NNODES + 127) / 128), dim3(NTH), 0, stream>>>(
        nodef, edgef, senders, receivers, img_n,
        bn1, bn2, bn3, gn, begn, aggb, ybuf, out_node);
}

// Round 8
// 350.883 us; speedup vs baseline: 1.0171x; 1.0171x over previous
//
#include <hip/hip_runtime.h>

#define NNODES 50000
#define NEDGES 200000
#define DD 128
#define LN_EPS 1e-5f
#define NTH 256

typedef __attribute__((ext_vector_type(8))) short bf16x8;
typedef __attribute__((ext_vector_type(4))) float f32x4;
typedef __attribute__((ext_vector_type(16))) float f32x16;

template<int N> struct ic { static constexpr int value = N; };

__device__ __forceinline__ unsigned short bfr(float f) {
    union { float f; unsigned u; } v; v.f = f;
    return (unsigned short)((v.u + 0x7fffu + ((v.u >> 16) & 1u)) >> 16);
}

// ---------------------------------------------------------------------------
// Weight image, coalesced-frag layout (identical math to r7, which passed).
// Per k32 chunk c (8 KB): byte = c*8192 + nt*2048 + ks*512 + n32*16
//   content: Wt[n = nt*32+n32][k = c*32 + ks*8 + e], e=0..7 (bf16)
// ---------------------------------------------------------------------------
__global__ void build_wimg(const float* __restrict__ We1, const float* __restrict__ We2,
                           const float* __restrict__ We3, const float* __restrict__ Wn1,
                           const float* __restrict__ Wn2, const float* __restrict__ Wn3,
                           char* __restrict__ img_e, char* __restrict__ img_n) {
    int tid = blockIdx.x * NTH + threadIdx.x;
    const float* W; char* dst; int q;
    if      (tid <  6144) { W = We1; dst = img_e;             q = tid;         }
    else if (tid <  8192) { W = We2; dst = img_e + 12 * 8192; q = tid - 6144;  }
    else if (tid < 10240) { W = We3; dst = img_e + 16 * 8192; q = tid - 8192;  }
    else if (tid < 14336) { W = Wn1; dst = img_n;             q = tid - 10240; }
    else if (tid < 16384) { W = Wn2; dst = img_n + 8 * 8192;  q = tid - 14336; }
    else if (tid < 18432) { W = Wn3; dst = img_n + 12 * 8192; q = tid - 16384; }
    else return;
    int c = q >> 9, rem = q & 511;
    int nt = rem >> 7, r2 = rem & 127, ks = r2 >> 5, n32 = r2 & 31;
    int n = nt * 32 + n32;
    int k0 = c * 32 + ks * 8;
    unsigned short o[8];
    #pragma unroll
    for (int e = 0; e < 8; ++e)
        o[e] = bfr(W[(size_t)(k0 + e) * DD + n]);
    uint4 val;
    val.x = (unsigned)o[0] | ((unsigned)o[1] << 16);
    val.y = (unsigned)o[2] | ((unsigned)o[3] << 16);
    val.z = (unsigned)o[4] | ((unsigned)o[5] << 16);
    val.w = (unsigned)o[6] | ((unsigned)o[7] << 16);
    *(uint4*)(dst + (size_t)c * 8192 + nt * 2048 + ks * 512 + n32 * 16) = val;
}

// ---------------------------------------------------------------------------
// Fused: nodef -> bf16 mirror (nodb) + receiver histogram.
// Grid must satisfy grid*NTH >= NEDGES (launched with 1024 blocks).
// ---------------------------------------------------------------------------
__global__ __launch_bounds__(NTH)
void cvt_histo(const float* __restrict__ nodef, const int* __restrict__ recv,
               uint4* __restrict__ nodb, int* __restrict__ cnt) {
    const int tid0 = blockIdx.x * NTH + threadIdx.x;
    if (tid0 < NEDGES) atomicAdd(&cnt[recv[tid0]], 1);
    const int NG = NNODES * 16;   // groups of 8 floats
    for (int g = tid0; g < NG; g += gridDim.x * NTH) {
        f32x4 a = ((const f32x4*)nodef)[g * 2];
        f32x4 b = ((const f32x4*)nodef)[g * 2 + 1];
        uint4 o;
        o.x = (unsigned)bfr(a[0]) | ((unsigned)bfr(a[1]) << 16);
        o.y = (unsigned)bfr(a[2]) | ((unsigned)bfr(a[3]) << 16);
        o.z = (unsigned)bfr(b[0]) | ((unsigned)bfr(b[1]) << 16);
        o.w = (unsigned)bfr(b[2]) | ((unsigned)bfr(b[3]) << 16);
        nodb[g] = o;
    }
}

// ---------------------------------------------------------------------------
// CSR: 2-level scan (256 partials) + fill
// ---------------------------------------------------------------------------
__global__ __launch_bounds__(NTH)
void csr_scan1(const int* __restrict__ cnt, int* __restrict__ part) {
    __shared__ int red[NTH];
    const int b = blockIdx.x, t = threadIdx.x;
    const int base = b * 196;
    int s = 0;
    for (int i = t; i < 196; i += NTH) {
        int idx = base + i;
        if (idx < NNODES) s += cnt[idx];
    }
    red[t] = s;
    __syncthreads();
    for (int d = NTH / 2; d > 0; d >>= 1) {
        if (t < d) red[t] += red[t + d];
        __syncthreads();
    }
    if (t == 0) part[b] = red[0];
}

__global__ __launch_bounds__(NTH)
void csr_scan2(const int* __restrict__ cnt, const int* __restrict__ part,
               int* __restrict__ off, int* __restrict__ cursor) {
    __shared__ int sp[NTH];
    const int t = threadIdx.x;
    sp[t] = part[t];
    __syncthreads();
    for (int d = 1; d < NTH; d <<= 1) {
        int v = (t >= d) ? sp[t - d] : 0;
        __syncthreads();
        sp[t] += v;
        __syncthreads();
    }
    int run = (t == 0) ? 0 : sp[t - 1];
    const int base = t * 196;
    for (int i = 0; i < 196; ++i) {
        int idx = base + i;
        if (idx < NNODES) { off[idx] = run; cursor[idx] = run; run += cnt[idx]; }
    }
    if (t == NTH - 1) off[NNODES] = NEDGES;
}

__global__ void csr_fill(const int* __restrict__ recv, int* __restrict__ cursor,
                         int* __restrict__ elist) {
    int e = blockIdx.x * NTH + threadIdx.x;
    if (e < NEDGES) {
        int p = atomicAdd(&cursor[recv[e]], 1);
        elist[p] = e;
    }
}

// ---------------------------------------------------------------------------
// Aggregate (bf16): aggb[n] = sum over receiver-edges of ybuf[e]; unroll 4.
// ---------------------------------------------------------------------------
__global__ __launch_bounds__(NTH)
void aggregate(const unsigned* __restrict__ ybuf,
               const int* __restrict__ off, const int* __restrict__ elist,
               unsigned* __restrict__ aggb) {
    const int n = blockIdx.x * 4 + (threadIdx.x >> 6);
    const int l = threadIdx.x & 63;
    if (n >= NNODES) return;
    const int j0 = off[n], j1 = off[n + 1];
    float sx = 0.f, sy = 0.f;
    int j = j0;
    for (; j + 4 <= j1; j += 4) {
        const int e0 = elist[j], e1 = elist[j + 1], e2 = elist[j + 2], e3 = elist[j + 3];
        unsigned v0 = ybuf[(size_t)e0 * 64 + l];
        unsigned v1 = ybuf[(size_t)e1 * 64 + l];
        unsigned v2 = ybuf[(size_t)e2 * 64 + l];
        unsigned v3 = ybuf[(size_t)e3 * 64 + l];
        sx += __uint_as_float(v0 << 16) + __uint_as_float(v1 << 16)
            + __uint_as_float(v2 << 16) + __uint_as_float(v3 << 16);
        sy += __uint_as_float(v0 & 0xffff0000u) + __uint_as_float(v1 & 0xffff0000u)
            + __uint_as_float(v2 & 0xffff0000u) + __uint_as_float(v3 & 0xffff0000u);
    }
    for (; j < j1; ++j) {
        unsigned v = ybuf[(size_t)elist[j] * 64 + l];
        sx += __uint_as_float(v << 16);
        sy += __uint_as_float(v & 0xffff0000u);
    }
    aggb[(size_t)n * 64 + l] = (unsigned)bfr(sx) | ((unsigned)bfr(sy) << 16);
}

// ---------------------------------------------------------------------------
// Fused MLP, 32x32x16 MFMA, barrier-free, deep static register pipelines.
// MODE 0 = edge (K=384), MODE 1 = node (K=256).
// 4 waves x 32 rows = 128 rows/block; waves independent.
// A: 3-slot half-chunk rotation from L2-hot image.
// B: bf16 gathers, 6-chunk rotation (refill at chunk end -> no WAR);
//    edge chunks 8..11 stream edgef fp32 with 2-slot rotation + consume cvt.
// H1/H2: wave-private swizzled LDS (no barriers).
// ---------------------------------------------------------------------------
template<int MODE>
__global__ __launch_bounds__(NTH, 2)
void mgn_mfma(const float* __restrict__ nodef, const float* __restrict__ edgef,
              const unsigned short* __restrict__ nodb,
              const int* __restrict__ senders, const int* __restrict__ receivers,
              const char* __restrict__ img,
              const float* __restrict__ b1, const float* __restrict__ b2,
              const float* __restrict__ b3,
              const float* __restrict__ gamma, const float* __restrict__ beta,
              const unsigned short* __restrict__ aggb, unsigned* __restrict__ ybuf,
              float* __restrict__ outp)
{
    __shared__ char Hb[4 * 8192];     // per-wave 32 rows x 128 k bf16, swizzled

    const int t  = threadIdx.x;
    const int w  = t >> 6;
    const int l  = t & 63;
    const int ln = l & 31;            // A: weight col n32 | B/C: X row m32
    const int hi = l >> 5;
    const int row0 = blockIdx.x * 128;
    const int gm = row0 + w * 32 + ln;
    constexpr int NROWS = (MODE == 0) ? NEDGES : NNODES;
    constexpr int NK1   = (MODE == 0) ? 12 : 8;
    constexpr int NCH   = NK1 + 8;
    const int gmc = gm < NROWS ? gm : NROWS - 1;
    const int sxH = ln & 15;

    int srow = 0, rrow = 0;
    if (MODE == 0) { srow = senders[gmc]; rrow = receivers[gmc]; }

    const f32x16 fz = {0.f,0.f,0.f,0.f,0.f,0.f,0.f,0.f,
                       0.f,0.f,0.f,0.f,0.f,0.f,0.f,0.f};
    f32x16 acc[4];
    #pragma unroll
    for (int nt = 0; nt < 4; ++nt) acc[nt] = fz;

    bf16x8 aS[3][4];    // A half-chunk rotation
    bf16x8 bS[6][2];    // bf16 B rotation (chunks 0..7)
    f32x4  fS[2][4];    // fp32 B rotation (edge chunks 8..11)

    auto loadA = [&](int h, bf16x8* dst) {
        const char* p = img + (size_t)(h >> 1) * 8192
                      + (size_t)(((h & 1) * 2 + hi) * 512) + ln * 16;
        #pragma unroll
        for (int nt = 0; nt < 4; ++nt)
            dst[nt] = *(const bf16x8*)(p + nt * 2048);
    };

    // bf16 B gather for chunk c (<8)
    auto loadBB = [&](auto CC, bf16x8* dst) {
        constexpr int c = decltype(CC)::value;
        const unsigned short* base;
        if constexpr (MODE == 0) {
            base = (c < 4) ? nodb + (size_t)srow * DD : nodb + (size_t)rrow * DD;
        } else {
            base = (c < 4) ? nodb + (size_t)gmc * DD : aggb + (size_t)gmc * DD;
        }
        const char* p = (const char*)base + (c & 3) * 64 + hi * 16;
        dst[0] = *(const bf16x8*)p;
        dst[1] = *(const bf16x8*)(p + 32);
    };

    // fp32 B stream from edgef (edge chunks 8..11)
    auto loadBF = [&](auto CC, f32x4* dst) {
        constexpr int c = decltype(CC)::value;
        const float* p = edgef + (size_t)gmc * DD + (c & 3) * 32 + hi * 8;
        dst[0] = *(const f32x4*)p;
        dst[1] = *(const f32x4*)(p + 4);
        dst[2] = *(const f32x4*)(p + 16);
        dst[3] = *(const f32x4*)(p + 20);
    };

    auto cvtB = [&](const f32x4* br) {
        bf16x8 r;
        #pragma unroll
        for (int i = 0; i < 4; ++i) r[i]     = (short)bfr(br[0][i]);
        #pragma unroll
        for (int i = 0; i < 4; ++i) r[4 + i] = (short)bfr(br[1][i]);
        return r;
    };

    auto loadBH = [&](int ks, int kh) {
        const char* p = Hb + w * 8192 + ln * 256
                      + (((ks * 4 + kh * 2 + hi) ^ sxH) << 4);
        return *(const bf16x8*)p;
    };

    auto getB = [&](auto CC, int kh) -> bf16x8 {
        constexpr int c = decltype(CC)::value;
        if constexpr (c >= NK1) {
            return loadBH((c - NK1) & 3, kh);
        } else if constexpr (MODE == 0 && c >= 8) {
            return cvtB(&fS[c & 1][kh * 2]);
        } else {
            return bS[c % 6][kh];
        }
    };

    auto epiH = [&](const float* bias) {
        #pragma unroll
        for (int nt = 0; nt < 4; ++nt) {
            #pragma unroll
            for (int rq = 0; rq < 4; ++rq) {
                f32x4 bv = *(const f32x4*)(bias + nt * 32 + rq * 8 + hi * 4);
                unsigned short h[4];
                #pragma unroll
                for (int j = 0; j < 4; ++j)
                    h[j] = bfr(fmaxf(acc[nt][rq * 4 + j] + bv[j], 0.f));
                char* p = Hb + w * 8192 + ln * 256
                        + (((nt * 4 + rq) ^ sxH) << 4) + hi * 8;
                unsigned lo = (unsigned)h[0] | ((unsigned)h[1] << 16);
                unsigned hx = (unsigned)h[2] | ((unsigned)h[3] << 16);
                *(unsigned long long*)p =
                    (unsigned long long)lo | ((unsigned long long)hx << 32);
            }
            acc[nt] = fz;
        }
    };

    auto chunkfn = [&](auto CC) {
        constexpr int c = decltype(CC)::value;
        constexpr int h0 = 2 * c, h1 = 2 * c + 1;
        // half 0: prefetch A(h0+2), consume aS[h0%3]
        if constexpr (h0 + 2 < 2 * NCH) loadA(h0 + 2, aS[(h0 + 2) % 3]);
        {
            bf16x8 b0 = getB(CC, 0);
            #pragma unroll
            for (int nt = 0; nt < 4; ++nt)
                acc[nt] = __builtin_amdgcn_mfma_f32_32x32x16_bf16(
                    aS[h0 % 3][nt], b0, acc[nt], 0, 0, 0);
        }
        // half 1: prefetch A(h1+2), consume aS[h1%3]
        if constexpr (h1 + 2 < 2 * NCH) loadA(h1 + 2, aS[(h1 + 2) % 3]);
        {
            bf16x8 b1 = getB(CC, 1);
            #pragma unroll
            for (int nt = 0; nt < 4; ++nt)
                acc[nt] = __builtin_amdgcn_mfma_f32_32x32x16_bf16(
                    aS[h1 % 3][nt], b1, acc[nt], 0, 0, 0);
        }
        // refills at chunk end (slot just freed -> no WAR on in-flight data)
        if constexpr (c + 6 < 8) loadBB(ic<c + 6>{}, bS[(c + 6) % 6]);
        if constexpr (MODE == 0 && c >= 6 && c <= 9) loadBF(ic<c + 2>{}, fS[(c + 2) & 1]);
    };

    // prologue: B chunks 0..5, A halves 0..1
    loadBB(ic<0>{}, bS[0]); loadBB(ic<1>{}, bS[1]); loadBB(ic<2>{}, bS[2]);
    loadBB(ic<3>{}, bS[3]); loadBB(ic<4>{}, bS[4]); loadBB(ic<5>{}, bS[5]);
    loadA(0, aS[0]); loadA(1, aS[1]);

#define CH(C)                                                                \
    if constexpr ((C) < NCH) {                                               \
        chunkfn(ic<(C)>{});                                                  \
        if constexpr ((C) == NK1 - 1) epiH(b1);                              \
        if constexpr ((C) == NK1 + 3) epiH(b2);                              \
    }
    CH(0)  CH(1)  CH(2)  CH(3)  CH(4)  CH(5)  CH(6)  CH(7)
    CH(8)  CH(9)  CH(10) CH(11) CH(12) CH(13) CH(14) CH(15)
    CH(16) CH(17) CH(18) CH(19)
#undef CH

    // ================= bias3 + LayerNorm + residual (+ ybuf) =================
    float vsum = 0.f, vsq = 0.f;
    #pragma unroll
    for (int nt = 0; nt < 4; ++nt) {
        #pragma unroll
        for (int rq = 0; rq < 4; ++rq) {
            f32x4 bv = *(const f32x4*)(b3 + nt * 32 + rq * 8 + hi * 4);
            #pragma unroll
            for (int j = 0; j < 4; ++j) {
                float v = acc[nt][rq * 4 + j] + bv[j];
                acc[nt][rq * 4 + j] = v;
                vsum += v; vsq += v * v;
            }
        }
    }
    vsum += __shfl_xor(vsum, 32);
    vsq  += __shfl_xor(vsq, 32);
    const float mu = vsum * (1.f / DD);
    const float rs = rsqrtf(vsq * (1.f / DD) - mu * mu + LN_EPS);

    if (gm < NROWS) {
        const float* resid = ((MODE == 0) ? edgef : nodef) + (size_t)gm * DD;
        #pragma unroll
        for (int nt = 0; nt < 4; ++nt) {
            #pragma unroll
            for (int rq = 0; rq < 4; ++rq) {
                const int n0 = nt * 32 + rq * 8 + hi * 4;
                f32x4 gv = *(const f32x4*)(gamma + n0);
                f32x4 bv = *(const f32x4*)(beta + n0);
                f32x4 rv = *(const f32x4*)(resid + n0);
                float y[4];
                f32x4 o;
                #pragma unroll
                for (int j = 0; j < 4; ++j) {
                    y[j] = (acc[nt][rq * 4 + j] - mu) * rs * gv[j] + bv[j];
                    o[j] = y[j] + rv[j];
                }
                *(f32x4*)(outp + (size_t)gm * DD + n0) = o;
                if (MODE == 0) {
                    unsigned lo = (unsigned)bfr(y[0]) | ((unsigned)bfr(y[1]) << 16);
                    unsigned hx = (unsigned)bfr(y[2]) | ((unsigned)bfr(y[3]) << 16);
                    *(unsigned long long*)((char*)ybuf + (size_t)gm * 256 + n0 * 2) =
                        (unsigned long long)lo | ((unsigned long long)hx << 32);
                }
            }
        }
    }
}

extern "C" void kernel_launch(void* const* d_in, const int* in_sizes, int n_in,
                              void* d_out, int out_size, void* d_ws, size_t ws_size,
                              hipStream_t stream) {
    const float* nodef = (const float*)d_in[0];
    const float* edgef = (const float*)d_in[1];
    const int* senders   = (const int*)d_in[2];
    const int* receivers = (const int*)d_in[3];
    const float* We1 = (const float*)d_in[4],  *be1 = (const float*)d_in[5];
    const float* We2 = (const float*)d_in[6],  *be2 = (const float*)d_in[7];
    const float* We3 = (const float*)d_in[8],  *be3 = (const float*)d_in[9];
    const float* ge  = (const float*)d_in[10], *bege = (const float*)d_in[11];
    const float* Wn1 = (const float*)d_in[12], *bn1 = (const float*)d_in[13];
    const float* Wn2 = (const float*)d_in[14], *bn2 = (const float*)d_in[15];
    const float* Wn3 = (const float*)d_in[16], *bn3 = (const float*)d_in[17];
    const float* gn  = (const float*)d_in[18], *begn = (const float*)d_in[19];

    float* out_node = (float*)d_out;
    float* out_edge = (float*)d_out + (size_t)NNODES * DD;

    char* ws = (char*)d_ws;
    size_t o = 0;
    unsigned short* aggb = (unsigned short*)(ws + o); o += (size_t)NNODES * 256;  // 12.8 MB
    unsigned* ybuf = (unsigned*)(ws + o);             o += (size_t)NEDGES * 256;  // 51.2 MB
    unsigned short* nodb = (unsigned short*)(ws + o); o += (size_t)NNODES * 256;  // 12.8 MB
    char* img_e = ws + o;           o += 20 * 8192;
    char* img_n = ws + o;           o += 16 * 8192;
    int* cnt    = (int*)(ws + o);   o += NNODES * 4;
    int* cursor = (int*)(ws + o);   o += NNODES * 4;
    int* off    = (int*)(ws + o);   o += (NNODES + 4) * 4;
    int* part   = (int*)(ws + o);   o += NTH * 4;
    int* elist  = (int*)(ws + o);   o += NEDGES * 4;

    hipMemsetAsync(cnt, 0, NNODES * 4, stream);
    cvt_histo<<<1024, NTH, 0, stream>>>(nodef, receivers, (uint4*)nodb, cnt);
    build_wimg<<<72, NTH, 0, stream>>>(We1, We2, We3, Wn1, Wn2, Wn3, img_e, img_n);
    csr_scan1<<<NTH, NTH, 0, stream>>>(cnt, part);
    csr_scan2<<<1, NTH, 0, stream>>>(cnt, part, off, cursor);
    csr_fill<<<(NEDGES + NTH - 1) / NTH, NTH, 0, stream>>>(receivers, cursor, elist);

    mgn_mfma<0><<<dim3((NEDGES + 127) / 128), dim3(NTH), 0, stream>>>(
        nodef, edgef, nodb, senders, receivers, img_e,
        be1, be2, be3, ge, bege, aggb, ybuf, out_edge);

    aggregate<<<(NNODES + 3) / 4, NTH, 0, stream>>>(ybuf, off, elist, (unsigned*)aggb);

    mgn_mfma<1><<<dim3((NNODES + 127) / 128), dim3(NTH), 0, stream>>>(
        nodef, edgef, nodb, senders, receivers, img_n,
        bn1, bn2, bn3, gn, begn, aggb, ybuf, out_node);
}

// Round 10
// 321.283 us; speedup vs baseline: 1.1108x; 1.0921x over previous
//
#include <hip/hip_runtime.h>

#define NNODES 50000
#define NEDGES 200000
#define DD 128
#define LN_EPS 1e-5f
#define NTH 256

typedef __attribute__((ext_vector_type(8))) short bf16x8;
typedef __attribute__((ext_vector_type(4))) float f32x4;
typedef __attribute__((ext_vector_type(16))) float f32x16;

template<int N> struct ic { static constexpr int value = N; };

__device__ __forceinline__ unsigned short bfr(float f) {
    union { float f; unsigned u; } v; v.f = f;
    return (unsigned short)((v.u + 0x7fffu + ((v.u >> 16) & 1u)) >> 16);
}
__device__ __forceinline__ unsigned pk2(float a, float b) {
    return (unsigned)bfr(a) | ((unsigned)bfr(b) << 16);
}
__device__ __forceinline__ void gload_lds16(const void* g, void* l) {
    __builtin_amdgcn_global_load_lds(
        (const __attribute__((address_space(1))) void*)g,
        (__attribute__((address_space(3))) void*)l, 16, 0, 0);
}

// ---------------------------------------------------------------------------
// Weight image for 32x32x16 MFMA (r6-proven, low-conflict swizzle).
// Per k32 chunk c (8 KB): granule(nt, n32, ks):
//   byte = c*8192 + nt*2048 + n32*64 + ((ks ^ ((n32 + (n32>>2)) & 3)) << 4)
//   content: Wt[n = nt*32+n32][k = c*32 + ks*8 + e], e=0..7 (bf16)
// global_load_lds copies linearly -> LDS layout == image layout (rule 21).
// ---------------------------------------------------------------------------
__global__ void build_wimg(const float* __restrict__ We1, const float* __restrict__ We2,
                           const float* __restrict__ We3, const float* __restrict__ Wn1,
                           const float* __restrict__ Wn2, const float* __restrict__ Wn3,
                           char* __restrict__ img_e, char* __restrict__ img_n) {
    int tid = blockIdx.x * NTH + threadIdx.x;
    const float* W; char* dst; int q;
    if      (tid <  6144) { W = We1; dst = img_e;             q = tid;         }
    else if (tid <  8192) { W = We2; dst = img_e + 12 * 8192; q = tid - 6144;  }
    else if (tid < 10240) { W = We3; dst = img_e + 16 * 8192; q = tid - 8192;  }
    else if (tid < 14336) { W = Wn1; dst = img_n;             q = tid - 10240; }
    else if (tid < 16384) { W = Wn2; dst = img_n + 8 * 8192;  q = tid - 14336; }
    else if (tid < 18432) { W = Wn3; dst = img_n + 12 * 8192; q = tid - 16384; }
    else return;
    int c = q >> 9, rem = q & 511;
    int nt = rem >> 7, r2 = rem & 127, n32 = r2 >> 2, ks = r2 & 3;
    int n = nt * 32 + n32;
    int sx = (n32 + (n32 >> 2)) & 3;
    int k0 = c * 32 + ks * 8;
    unsigned short o[8];
    #pragma unroll
    for (int e = 0; e < 8; ++e)
        o[e] = bfr(W[(size_t)(k0 + e) * DD + n]);
    uint4 val;
    val.x = (unsigned)o[0] | ((unsigned)o[1] << 16);
    val.y = (unsigned)o[2] | ((unsigned)o[3] << 16);
    val.z = (unsigned)o[4] | ((unsigned)o[5] << 16);
    val.w = (unsigned)o[6] | ((unsigned)o[7] << 16);
    *(uint4*)(dst + (size_t)c * 8192 + nt * 2048 + n32 * 64 + ((ks ^ sx) << 4)) = val;
}

// ---------------------------------------------------------------------------
// Fused: nodef -> bf16 mirror + receiver histogram (r8-proven).
// ---------------------------------------------------------------------------
__global__ __launch_bounds__(NTH)
void cvt_histo(const float* __restrict__ nodef, const int* __restrict__ recv,
               uint4* __restrict__ nodb, int* __restrict__ cnt) {
    const int tid0 = blockIdx.x * NTH + threadIdx.x;
    if (tid0 < NEDGES) atomicAdd(&cnt[recv[tid0]], 1);
    const int NG = NNODES * 16;
    for (int g = tid0; g < NG; g += gridDim.x * NTH) {
        f32x4 a = ((const f32x4*)nodef)[g * 2];
        f32x4 b = ((const f32x4*)nodef)[g * 2 + 1];
        uint4 o;
        o.x = pk2(a[0], a[1]); o.y = pk2(a[2], a[3]);
        o.z = pk2(b[0], b[1]); o.w = pk2(b[2], b[3]);
        nodb[g] = o;
    }
}

// ---------------------------------------------------------------------------
// CSR: 2-level scan + fill (r8-proven)
// ---------------------------------------------------------------------------
__global__ __launch_bounds__(NTH)
void csr_scan1(const int* __restrict__ cnt, int* __restrict__ part) {
    __shared__ int red[NTH];
    const int b = blockIdx.x, t = threadIdx.x;
    const int base = b * 196;
    int s = 0;
    for (int i = t; i < 196; i += NTH) {
        int idx = base + i;
        if (idx < NNODES) s += cnt[idx];
    }
    red[t] = s;
    __syncthreads();
    for (int d = NTH / 2; d > 0; d >>= 1) {
        if (t < d) red[t] += red[t + d];
        __syncthreads();
    }
    if (t == 0) part[b] = red[0];
}

__global__ __launch_bounds__(NTH)
void csr_scan2(const int* __restrict__ cnt, const int* __restrict__ part,
               int* __restrict__ off, int* __restrict__ cursor) {
    __shared__ int sp[NTH];
    const int t = threadIdx.x;
    sp[t] = part[t];
    __syncthreads();
    for (int d = 1; d < NTH; d <<= 1) {
        int v = (t >= d) ? sp[t - d] : 0;
        __syncthreads();
        sp[t] += v;
        __syncthreads();
    }
    int run = (t == 0) ? 0 : sp[t - 1];
    const int base = t * 196;
    for (int i = 0; i < 196; ++i) {
        int idx = base + i;
        if (idx < NNODES) { off[idx] = run; cursor[idx] = run; run += cnt[idx]; }
    }
    if (t == NTH - 1) off[NNODES] = NEDGES;
}

__global__ void csr_fill(const int* __restrict__ recv, int* __restrict__ cursor,
                         int* __restrict__ elist) {
    int e = blockIdx.x * NTH + threadIdx.x;
    if (e < NEDGES) {
        int p = atomicAdd(&cursor[recv[e]], 1);
        elist[p] = e;
    }
}

// ---------------------------------------------------------------------------
// Aggregate (bf16, r8-proven): aggb[n] = sum over receiver-edges of ybuf[e]
// ---------------------------------------------------------------------------
__global__ __launch_bounds__(NTH)
void aggregate(const unsigned* __restrict__ ybuf,
               const int* __restrict__ off, const int* __restrict__ elist,
               unsigned* __restrict__ aggb) {
    const int n = blockIdx.x * 4 + (threadIdx.x >> 6);
    const int l = threadIdx.x & 63;
    if (n >= NNODES) return;
    const int j0 = off[n], j1 = off[n + 1];
    float sx = 0.f, sy = 0.f;
    int j = j0;
    for (; j + 4 <= j1; j += 4) {
        unsigned v0 = ybuf[(size_t)elist[j] * 64 + l];
        unsigned v1 = ybuf[(size_t)elist[j + 1] * 64 + l];
        unsigned v2 = ybuf[(size_t)elist[j + 2] * 64 + l];
        unsigned v3 = ybuf[(size_t)elist[j + 3] * 64 + l];
        sx += __uint_as_float(v0 << 16) + __uint_as_float(v1 << 16)
            + __uint_as_float(v2 << 16) + __uint_as_float(v3 << 16);
        sy += __uint_as_float(v0 & 0xffff0000u) + __uint_as_float(v1 & 0xffff0000u)
            + __uint_as_float(v2 & 0xffff0000u) + __uint_as_float(v3 & 0xffff0000u);
    }
    for (; j < j1; ++j) {
        unsigned v = ybuf[(size_t)elist[j] * 64 + l];
        sx += __uint_as_float(v << 16);
        sy += __uint_as_float(v & 0xffff0000u);
    }
    aggb[(size_t)n * 64 + l] = pk2(sx, sy);
}

// ---------------------------------------------------------------------------
// Fused MLP, 32x32x16 MFMA (r6-proven structure + r8-proven bf16 gathers).
// MODE 0 = edge (K=384), MODE 1 = node (K=256).
// 4 waves x 32 rows = 128 rows/block.
// A: 5-buffer LDS rotation (lead 3) via global_load_lds, counted vmcnt
//    (margin -2), 1 s_barrier/chunk.
// B: bf16 gathers (nodb/aggb) lead-2, 3-slot rotation; edge chunks 8..11
//    stream edgef fp32, 3-slot rotation + consume-time cvt.
// H1/H2: wave-private swizzled LDS (r6-proven epiH/loadBH).
// ---------------------------------------------------------------------------
template<int MODE>
__global__ __launch_bounds__(NTH, 2)
void mgn_mfma(const float* __restrict__ nodef, const float* __restrict__ edgef,
              const unsigned short* __restrict__ nodb,
              const int* __restrict__ senders, const int* __restrict__ receivers,
              const char* __restrict__ img,
              const float* __restrict__ b1, const float* __restrict__ b2,
              const float* __restrict__ b3,
              const float* __restrict__ gamma, const float* __restrict__ beta,
              const unsigned short* __restrict__ aggb, unsigned* __restrict__ ybuf,
              float* __restrict__ outp)
{
    __shared__ char Wbuf[5 * 8192];   // 5 rotating k32 weight chunks
    __shared__ char Hb[4 * 8192];     // per-wave 32 rows x 128 k bf16, swizzled

    const int t  = threadIdx.x;
    const int w  = t >> 6;
    const int l  = t & 63;
    const int ln = l & 31;
    const int hi = l >> 5;
    const int row0 = blockIdx.x * 128;
    const int gm = row0 + w * 32 + ln;
    constexpr int NROWS = (MODE == 0) ? NEDGES : NNODES;
    constexpr int NK1   = (MODE == 0) ? 12 : 8;
    constexpr int NCH   = NK1 + 8;
    const int gmc = gm < NROWS ? gm : NROWS - 1;
    const int sxA = (ln + (ln >> 2)) & 3;
    const int sxH = ln & 15;

    int srow = 0, rrow = 0;
    if (MODE == 0) { srow = senders[gmc]; rrow = receivers[gmc]; }

    const f32x16 fz = {0.f,0.f,0.f,0.f,0.f,0.f,0.f,0.f,
                       0.f,0.f,0.f,0.f,0.f,0.f,0.f,0.f};
    f32x16 acc[4];
    #pragma unroll
    for (int nt = 0; nt < 4; ++nt) acc[nt] = fz;

    bf16x8 bS[3][2];   // bf16 B rotation, lead 2
    f32x4  fS[3][4];   // fp32 B rotation (edge chunks 8..11), lead 2

    // ---- stage weight chunk c into Wbuf[c%5] (r6-proven linear copy) ----
    auto stageW = [&](int c) {
        const char* src = img + (size_t)c * 8192 + t * 16;
        char* dstl = Wbuf + (c % 5) * 8192 + t * 16;
        gload_lds16(src, dstl);
        gload_lds16(src + 4096, dstl + 4096);
    };

    // ---- bf16 B gather ----
    auto loadBB = [&](auto CC, bf16x8* dst) {
        constexpr int c = decltype(CC)::value;
        const unsigned short* base;
        if constexpr (MODE == 0) {
            base = (c < 4) ? nodb + (size_t)srow * DD : nodb + (size_t)rrow * DD;
        } else {
            base = (c < 4) ? nodb + (size_t)gmc * DD : aggb + (size_t)gmc * DD;
        }
        const char* p = (const char*)base + (c & 3) * 64 + hi * 16;
        dst[0] = *(const bf16x8*)p;         // kh = 0
        dst[1] = *(const bf16x8*)(p + 32);  // kh = 1
    };

    // ---- fp32 B stream from edgef (edge chunks 8..11) ----
    auto loadBF = [&](auto CC, f32x4* dst) {
        constexpr int c = decltype(CC)::value;
        const float* p = edgef + (size_t)gmc * DD + (c & 3) * 32 + hi * 8;
        dst[0] = *(const f32x4*)p;
        dst[1] = *(const f32x4*)(p + 4);
        dst[2] = *(const f32x4*)(p + 16);
        dst[3] = *(const f32x4*)(p + 20);
    };

    auto cvtB = [&](const f32x4* br) {
        union { unsigned u[4]; bf16x8 v; } r;
        r.u[0] = pk2(br[0][0], br[0][1]);
        r.u[1] = pk2(br[0][2], br[0][3]);
        r.u[2] = pk2(br[1][0], br[1][1]);
        r.u[3] = pk2(br[1][2], br[1][3]);
        return r.v;
    };

    // ---- H read: slot sk = ks*4 + kh*2 + hi, swizzled (r6-proven) ----
    auto loadBH = [&](int ks, int kh) {
        const char* p = Hb + w * 8192 + ln * 256
                      + (((ks * 4 + kh * 2 + hi) ^ sxH) << 4);
        return *(const bf16x8*)p;
    };

    auto getB = [&](auto CC, int kh) -> bf16x8 {
        constexpr int c = decltype(CC)::value;
        if constexpr (c >= NK1) {
            return loadBH((c - NK1) & 3, kh);
        } else if constexpr (MODE == 0 && c >= 8) {
            return cvtB(&fS[c % 3][kh * 2]);
        } else {
            return bS[c % 3][kh];
        }
    };

    // ---- compute chunk c from LDS weights (r6-proven) ----
    auto compute = [&](auto CC) {
        constexpr int c = decltype(CC)::value;
        const char* bp = Wbuf + (c % 5) * 8192 + ln * 64;
        #pragma unroll
        for (int kh = 0; kh < 2; ++kh) {
            bf16x8 b = getB(CC, kh);
            #pragma unroll
            for (int nt = 0; nt < 4; ++nt) {
                bf16x8 a = *(const bf16x8*)(bp + nt * 2048
                            + (((kh * 2 + hi) ^ sxA) << 4));
                acc[nt] = __builtin_amdgcn_mfma_f32_32x32x16_bf16(a, b, acc[nt], 0, 0, 0);
            }
        }
    };

    // ---- bias + relu -> Hb (r6-proven), reset acc ----
    auto epiH = [&](const float* bias) {
        #pragma unroll
        for (int nt = 0; nt < 4; ++nt) {
            #pragma unroll
            for (int rq = 0; rq < 4; ++rq) {
                f32x4 bv = *(const f32x4*)(bias + nt * 32 + rq * 8 + hi * 4);
                unsigned short h[4];
                #pragma unroll
                for (int j = 0; j < 4; ++j)
                    h[j] = bfr(fmaxf(acc[nt][rq * 4 + j] + bv[j], 0.f));
                char* p = Hb + w * 8192 + ln * 256
                        + (((nt * 4 + rq) ^ sxH) << 4) + hi * 8;
                unsigned lo = (unsigned)h[0] | ((unsigned)h[1] << 16);
                unsigned hx = (unsigned)h[2] | ((unsigned)h[3] << 16);
                *(unsigned long long*)p =
                    (unsigned long long)lo | ((unsigned long long)hx << 32);
            }
            acc[nt] = fz;
        }
    };

#define PITER(C, VM)                                                          \
    {                                                                         \
        if constexpr ((C) + 3 < NCH) stageW((C) + 3);                         \
        __builtin_amdgcn_sched_barrier(0);                                    \
        if constexpr ((C) + 2 < NK1) {                                        \
            if constexpr (MODE == 0 && (C) + 2 >= 8)                          \
                loadBF(ic<(C) + 2>{}, fS[((C) + 2) % 3]);                     \
            else                                                              \
                loadBB(ic<(C) + 2>{}, bS[((C) + 2) % 3]);                     \
        }                                                                     \
        __builtin_amdgcn_sched_barrier(0);                                    \
        asm volatile("s_waitcnt vmcnt(" #VM ")" ::: "memory");                \
        __builtin_amdgcn_sched_barrier(0);                                    \
        __builtin_amdgcn_s_barrier();                                         \
        __builtin_amdgcn_sched_barrier(0);                                    \
        compute(ic<(C)>{});                                                   \
    }

    // prologue: stages 0..2, B 0..1 (order pinned)
    stageW(0);
    __builtin_amdgcn_sched_barrier(0);
    loadBB(ic<0>{}, bS[0]);
    __builtin_amdgcn_sched_barrier(0);
    stageW(1);
    __builtin_amdgcn_sched_barrier(0);
    loadBB(ic<1>{}, bS[1]);
    __builtin_amdgcn_sched_barrier(0);
    stageW(2);
    __builtin_amdgcn_sched_barrier(0);

    if constexpr (MODE == 0) {
        PITER(0, 10)  PITER(1, 10)  PITER(2, 10)  PITER(3, 12)
        PITER(4, 12)  PITER(5, 12)  PITER(6, 14)  PITER(7, 16)
        PITER(8, 18)  PITER(9, 20)  PITER(10, 16) PITER(11, 12)
        epiH(b1);
        PITER(12, 8)  PITER(13, 4)  PITER(14, 4)  PITER(15, 4)
        epiH(b2);
        PITER(16, 4)  PITER(17, 2)  PITER(18, 0)  PITER(19, 0)
    } else {
        PITER(0, 10)  PITER(1, 10)  PITER(2, 10)  PITER(3, 12)
        PITER(4, 12)  PITER(5, 12)  PITER(6, 10)  PITER(7, 8)
        epiH(b1);
        PITER(8, 6)   PITER(9, 4)   PITER(10, 4)  PITER(11, 4)
        epiH(b2);
        PITER(12, 4)  PITER(13, 2)  PITER(14, 0)  PITER(15, 0)
    }
#undef PITER

    // ================= bias3 + LayerNorm + residual (+ ybuf) =================
    float vsum = 0.f, vsq = 0.f;
    #pragma unroll
    for (int nt = 0; nt < 4; ++nt) {
        #pragma unroll
        for (int rq = 0; rq < 4; ++rq) {
            f32x4 bv = *(const f32x4*)(b3 + nt * 32 + rq * 8 + hi * 4);
            #pragma unroll
            for (int j = 0; j < 4; ++j) {
                float v = acc[nt][rq * 4 + j] + bv[j];
                acc[nt][rq * 4 + j] = v;
                vsum += v; vsq += v * v;
            }
        }
    }
    vsum += __shfl_xor(vsum, 32);
    vsq  += __shfl_xor(vsq, 32);
    const float mu = vsum * (1.f / DD);
    const float rs = rsqrtf(vsq * (1.f / DD) - mu * mu + LN_EPS);

    if (gm < NROWS) {
        const float* resid = ((MODE == 0) ? edgef : nodef) + (size_t)gm * DD;
        #pragma unroll
        for (int nt = 0; nt < 4; ++nt) {
            #pragma unroll
            for (int rq = 0; rq < 4; ++rq) {
                const int n0 = nt * 32 + rq * 8 + hi * 4;
                f32x4 gv = *(const f32x4*)(gamma + n0);
                f32x4 bv = *(const f32x4*)(beta + n0);
                f32x4 rv = *(const f32x4*)(resid + n0);
                float y[4];
                f32x4 o;
                #pragma unroll
                for (int j = 0; j < 4; ++j) {
                    y[j] = (acc[nt][rq * 4 + j] - mu) * rs * gv[j] + bv[j];
                    o[j] = y[j] + rv[j];
                }
                *(f32x4*)(outp + (size_t)gm * DD + n0) = o;
                if (MODE == 0) {
                    unsigned long long pkd =
                        (unsigned long long)pk2(y[0], y[1])
                      | ((unsigned long long)pk2(y[2], y[3]) << 32);
                    *(unsigned long long*)((char*)ybuf + (size_t)gm * 256 + n0 * 2) = pkd;
                }
            }
        }
    }
}

extern "C" void kernel_launch(void* const* d_in, const int* in_sizes, int n_in,
                              void* d_out, int out_size, void* d_ws, size_t ws_size,
                              hipStream_t stream) {
    const float* nodef = (const float*)d_in[0];
    const float* edgef = (const float*)d_in[1];
    const int* senders   = (const int*)d_in[2];
    const int* receivers = (const int*)d_in[3];
    const float* We1 = (const float*)d_in[4],  *be1 = (const float*)d_in[5];
    const float* We2 = (const float*)d_in[6],  *be2 = (const float*)d_in[7];
    const float* We3 = (const float*)d_in[8],  *be3 = (const float*)d_in[9];
    const float* ge  = (const float*)d_in[10], *bege = (const float*)d_in[11];
    const float* Wn1 = (const float*)d_in[12], *bn1 = (const float*)d_in[13];
    const float* Wn2 = (const float*)d_in[14], *bn2 = (const float*)d_in[15];
    const float* Wn3 = (const float*)d_in[16], *bn3 = (const float*)d_in[17];
    const float* gn  = (const float*)d_in[18], *begn = (const float*)d_in[19];

    float* out_node = (float*)d_out;
    float* out_edge = (float*)d_out + (size_t)NNODES * DD;

    char* ws = (char*)d_ws;
    size_t o = 0;
    unsigned short* aggb = (unsigned short*)(ws + o); o += (size_t)NNODES * 256;
    unsigned* ybuf = (unsigned*)(ws + o);             o += (size_t)NEDGES * 256;
    unsigned short* nodb = (unsigned short*)(ws + o); o += (size_t)NNODES * 256;
    char* img_e = ws + o;           o += 20 * 8192;
    char* img_n = ws + o;           o += 16 * 8192;
    int* cnt    = (int*)(ws + o);   o += NNODES * 4;
    int* cursor = (int*)(ws + o);   o += NNODES * 4;
    int* off    = (int*)(ws + o);   o += (NNODES + 4) * 4;
    int* part   = (int*)(ws + o);   o += NTH * 4;
    int* elist  = (int*)(ws + o);   o += NEDGES * 4;

    hipMemsetAsync(cnt, 0, NNODES * 4, stream);
    cvt_histo<<<1024, NTH, 0, stream>>>(nodef, receivers, (uint4*)nodb, cnt);
    build_wimg<<<72, NTH, 0, stream>>>(We1, We2, We3, Wn1, Wn2, Wn3, img_e, img_n);
    csr_scan1<<<NTH, NTH, 0, stream>>>(cnt, part);
    csr_scan2<<<1, NTH, 0, stream>>>(cnt, part, off, cursor);
    csr_fill<<<(NEDGES + NTH - 1) / NTH, NTH, 0, stream>>>(receivers, cursor, elist);

    mgn_mfma<0><<<dim3((NEDGES + 127) / 128), dim3(NTH), 0, stream>>>(
        nodef, edgef, nodb, senders, receivers, img_e,
        be1, be2, be3, ge, bege, aggb, ybuf, out_edge);

    aggregate<<<(NNODES + 3) / 4, NTH, 0, stream>>>(ybuf, off, elist, (unsigned*)aggb);

    mgn_mfma<1><<<dim3((NNODES + 127) / 128), dim3(NTH), 0, stream>>>(
        nodef, edgef, nodb, senders, receivers, img_n,
        bn1, bn2, bn3, gn, begn, aggb, ybuf, out_node);
}

// Round 11
// 316.333 us; speedup vs baseline: 1.1282x; 1.0156x over previous
//
#include <hip/hip_runtime.h>

#define NNODES 50000
#define NEDGES 200000
#define DD 128
#define LN_EPS 1e-5f
#define NTH 256

typedef __attribute__((ext_vector_type(8))) short bf16x8;
typedef __attribute__((ext_vector_type(4))) float f32x4;
typedef __attribute__((ext_vector_type(16))) float f32x16;

template<int N> struct ic { static constexpr int value = N; };

__device__ __forceinline__ unsigned short bfr(float f) {
    union { float f; unsigned u; } v; v.f = f;
    return (unsigned short)((v.u + 0x7fffu + ((v.u >> 16) & 1u)) >> 16);
}
__device__ __forceinline__ unsigned pk2(float a, float b) {
    return (unsigned)bfr(a) | ((unsigned)bfr(b) << 16);
}
__device__ __forceinline__ void gload_lds16(const void* g, void* l) {
    __builtin_amdgcn_global_load_lds(
        (const __attribute__((address_space(1))) void*)g,
        (__attribute__((address_space(3))) void*)l, 16, 0, 0);
}

// ---------------------------------------------------------------------------
// Weight image for 32x32x16 MFMA (r6-proven, low-conflict swizzle).
// Per k32 chunk c (8 KB): granule(nt, n32, ks):
//   byte = c*8192 + nt*2048 + n32*64 + ((ks ^ ((n32 + (n32>>2)) & 3)) << 4)
//   content: Wt[n = nt*32+n32][k = c*32 + ks*8 + e], e=0..7 (bf16)
// ---------------------------------------------------------------------------
__global__ void build_wimg(const float* __restrict__ We1, const float* __restrict__ We2,
                           const float* __restrict__ We3, const float* __restrict__ Wn1,
                           const float* __restrict__ Wn2, const float* __restrict__ Wn3,
                           char* __restrict__ img_e, char* __restrict__ img_n) {
    int tid = blockIdx.x * NTH + threadIdx.x;
    const float* W; char* dst; int q;
    if      (tid <  6144) { W = We1; dst = img_e;             q = tid;         }
    else if (tid <  8192) { W = We2; dst = img_e + 12 * 8192; q = tid - 6144;  }
    else if (tid < 10240) { W = We3; dst = img_e + 16 * 8192; q = tid - 8192;  }
    else if (tid < 14336) { W = Wn1; dst = img_n;             q = tid - 10240; }
    else if (tid < 16384) { W = Wn2; dst = img_n + 8 * 8192;  q = tid - 14336; }
    else if (tid < 18432) { W = Wn3; dst = img_n + 12 * 8192; q = tid - 16384; }
    else return;
    int c = q >> 9, rem = q & 511;
    int nt = rem >> 7, r2 = rem & 127, n32 = r2 >> 2, ks = r2 & 3;
    int n = nt * 32 + n32;
    int sx = (n32 + (n32 >> 2)) & 3;
    int k0 = c * 32 + ks * 8;
    unsigned short o[8];
    #pragma unroll
    for (int e = 0; e < 8; ++e)
        o[e] = bfr(W[(size_t)(k0 + e) * DD + n]);
    uint4 val;
    val.x = (unsigned)o[0] | ((unsigned)o[1] << 16);
    val.y = (unsigned)o[2] | ((unsigned)o[3] << 16);
    val.z = (unsigned)o[4] | ((unsigned)o[5] << 16);
    val.w = (unsigned)o[6] | ((unsigned)o[7] << 16);
    *(uint4*)(dst + (size_t)c * 8192 + nt * 2048 + n32 * 64 + ((ks ^ sx) << 4)) = val;
}

// ---------------------------------------------------------------------------
// Fused: nodef -> bf16 mirror + receiver histogram (r8-proven).
// ---------------------------------------------------------------------------
__global__ __launch_bounds__(NTH)
void cvt_histo(const float* __restrict__ nodef, const int* __restrict__ recv,
               uint4* __restrict__ nodb, int* __restrict__ cnt) {
    const int tid0 = blockIdx.x * NTH + threadIdx.x;
    if (tid0 < NEDGES) atomicAdd(&cnt[recv[tid0]], 1);
    const int NG = NNODES * 16;
    for (int g = tid0; g < NG; g += gridDim.x * NTH) {
        f32x4 a = ((const f32x4*)nodef)[g * 2];
        f32x4 b = ((const f32x4*)nodef)[g * 2 + 1];
        uint4 o;
        o.x = pk2(a[0], a[1]); o.y = pk2(a[2], a[3]);
        o.z = pk2(b[0], b[1]); o.w = pk2(b[2], b[3]);
        nodb[g] = o;
    }
}

// ---------------------------------------------------------------------------
// CSR: 2-level scan + fill (fill now stores perm[e] = CSR position of edge e)
// ---------------------------------------------------------------------------
__global__ __launch_bounds__(NTH)
void csr_scan1(const int* __restrict__ cnt, int* __restrict__ part) {
    __shared__ int red[NTH];
    const int b = blockIdx.x, t = threadIdx.x;
    const int base = b * 196;
    int s = 0;
    for (int i = t; i < 196; i += NTH) {
        int idx = base + i;
        if (idx < NNODES) s += cnt[idx];
    }
    red[t] = s;
    __syncthreads();
    for (int d = NTH / 2; d > 0; d >>= 1) {
        if (t < d) red[t] += red[t + d];
        __syncthreads();
    }
    if (t == 0) part[b] = red[0];
}

__global__ __launch_bounds__(NTH)
void csr_scan2(const int* __restrict__ cnt, const int* __restrict__ part,
               int* __restrict__ off, int* __restrict__ cursor) {
    __shared__ int sp[NTH];
    const int t = threadIdx.x;
    sp[t] = part[t];
    __syncthreads();
    for (int d = 1; d < NTH; d <<= 1) {
        int v = (t >= d) ? sp[t - d] : 0;
        __syncthreads();
        sp[t] += v;
        __syncthreads();
    }
    int run = (t == 0) ? 0 : sp[t - 1];
    const int base = t * 196;
    for (int i = 0; i < 196; ++i) {
        int idx = base + i;
        if (idx < NNODES) { off[idx] = run; cursor[idx] = run; run += cnt[idx]; }
    }
    if (t == NTH - 1) off[NNODES] = NEDGES;
}

__global__ void csr_fill(const int* __restrict__ recv, int* __restrict__ cursor,
                         int* __restrict__ perm) {
    int e = blockIdx.x * NTH + threadIdx.x;
    if (e < NEDGES) {
        int p = atomicAdd(&cursor[recv[e]], 1);
        perm[e] = p;
    }
}

// ---------------------------------------------------------------------------
// Aggregate (bf16): ybuf is CSR-ORDERED (edge kernel wrote y[e] at perm[e]),
// so node n's contributions are rows [off[n], off[n+1]) -- pure streaming.
// ---------------------------------------------------------------------------
__global__ __launch_bounds__(NTH)
void aggregate(const unsigned* __restrict__ ybuf,
               const int* __restrict__ off,
               unsigned* __restrict__ aggb) {
    const int n = blockIdx.x * 4 + (threadIdx.x >> 6);
    const int l = threadIdx.x & 63;
    if (n >= NNODES) return;
    const int j0 = off[n], j1 = off[n + 1];
    float sx = 0.f, sy = 0.f;
    int j = j0;
    for (; j + 4 <= j1; j += 4) {
        unsigned v0 = ybuf[(size_t)j * 64 + l];
        unsigned v1 = ybuf[(size_t)(j + 1) * 64 + l];
        unsigned v2 = ybuf[(size_t)(j + 2) * 64 + l];
        unsigned v3 = ybuf[(size_t)(j + 3) * 64 + l];
        sx += __uint_as_float(v0 << 16) + __uint_as_float(v1 << 16)
            + __uint_as_float(v2 << 16) + __uint_as_float(v3 << 16);
        sy += __uint_as_float(v0 & 0xffff0000u) + __uint_as_float(v1 & 0xffff0000u)
            + __uint_as_float(v2 & 0xffff0000u) + __uint_as_float(v3 & 0xffff0000u);
    }
    for (; j < j1; ++j) {
        unsigned v = ybuf[(size_t)j * 64 + l];
        sx += __uint_as_float(v << 16);
        sy += __uint_as_float(v & 0xffff0000u);
    }
    aggb[(size_t)n * 64 + l] = pk2(sx, sy);
}

// ---------------------------------------------------------------------------
// Fused MLP, 32x32x16 MFMA (r10-proven structure).
// vmcnt tables are now EXACT for stage-only retirement (FIFO-derived):
// the barrier no longer waits on random-latency B gathers -- those are
// retired per-wave by compiler-inserted waits after the barrier.
// MODE 0 edge also scatter-writes y rows at perm[e] (CSR order).
// ---------------------------------------------------------------------------
template<int MODE>
__global__ __launch_bounds__(NTH, 2)
void mgn_mfma(const float* __restrict__ nodef, const float* __restrict__ edgef,
              const unsigned short* __restrict__ nodb,
              const int* __restrict__ senders, const int* __restrict__ receivers,
              const int* __restrict__ perm,
              const char* __restrict__ img,
              const float* __restrict__ b1, const float* __restrict__ b2,
              const float* __restrict__ b3,
              const float* __restrict__ gamma, const float* __restrict__ beta,
              const unsigned short* __restrict__ aggb, unsigned* __restrict__ ybuf,
              float* __restrict__ outp)
{
    __shared__ char Wbuf[5 * 8192];   // 5 rotating k32 weight chunks
    __shared__ char Hb[4 * 8192];     // per-wave 32 rows x 128 k bf16, swizzled

    const int t  = threadIdx.x;
    const int w  = t >> 6;
    const int l  = t & 63;
    const int ln = l & 31;
    const int hi = l >> 5;
    const int row0 = blockIdx.x * 128;
    const int gm = row0 + w * 32 + ln;
    constexpr int NROWS = (MODE == 0) ? NEDGES : NNODES;
    constexpr int NK1   = (MODE == 0) ? 12 : 8;
    constexpr int NCH   = NK1 + 8;
    const int gmc = gm < NROWS ? gm : NROWS - 1;
    const int sxA = (ln + (ln >> 2)) & 3;
    const int sxH = ln & 15;

    int srow = 0, rrow = 0, prow = 0;
    if (MODE == 0) { srow = senders[gmc]; rrow = receivers[gmc]; prow = perm[gmc]; }

    const f32x16 fz = {0.f,0.f,0.f,0.f,0.f,0.f,0.f,0.f,
                       0.f,0.f,0.f,0.f,0.f,0.f,0.f,0.f};
    f32x16 acc[4];
    #pragma unroll
    for (int nt = 0; nt < 4; ++nt) acc[nt] = fz;

    bf16x8 bS[3][2];   // bf16 B rotation, lead 2
    f32x4  fS[3][4];   // fp32 B rotation (edge chunks 8..11), lead 2

    auto stageW = [&](int c) {
        const char* src = img + (size_t)c * 8192 + t * 16;
        char* dstl = Wbuf + (c % 5) * 8192 + t * 16;
        gload_lds16(src, dstl);
        gload_lds16(src + 4096, dstl + 4096);
    };

    auto loadBB = [&](auto CC, bf16x8* dst) {
        constexpr int c = decltype(CC)::value;
        const unsigned short* base;
        if constexpr (MODE == 0) {
            base = (c < 4) ? nodb + (size_t)srow * DD : nodb + (size_t)rrow * DD;
        } else {
            base = (c < 4) ? nodb + (size_t)gmc * DD : aggb + (size_t)gmc * DD;
        }
        const char* p = (const char*)base + (c & 3) * 64 + hi * 16;
        dst[0] = *(const bf16x8*)p;
        dst[1] = *(const bf16x8*)(p + 32);
    };

    auto loadBF = [&](auto CC, f32x4* dst) {
        constexpr int c = decltype(CC)::value;
        const float* p = edgef + (size_t)gmc * DD + (c & 3) * 32 + hi * 8;
        dst[0] = *(const f32x4*)p;
        dst[1] = *(const f32x4*)(p + 4);
        dst[2] = *(const f32x4*)(p + 16);
        dst[3] = *(const f32x4*)(p + 20);
    };

    auto cvtB = [&](const f32x4* br) {
        union { unsigned u[4]; bf16x8 v; } r;
        r.u[0] = pk2(br[0][0], br[0][1]);
        r.u[1] = pk2(br[0][2], br[0][3]);
        r.u[2] = pk2(br[1][0], br[1][1]);
        r.u[3] = pk2(br[1][2], br[1][3]);
        return r.v;
    };

    auto loadBH = [&](int ks, int kh) {
        const char* p = Hb + w * 8192 + ln * 256
                      + (((ks * 4 + kh * 2 + hi) ^ sxH) << 4);
        return *(const bf16x8*)p;
    };

    auto getB = [&](auto CC, int kh) -> bf16x8 {
        constexpr int c = decltype(CC)::value;
        if constexpr (c >= NK1) {
            return loadBH((c - NK1) & 3, kh);
        } else if constexpr (MODE == 0 && c >= 8) {
            return cvtB(&fS[c % 3][kh * 2]);
        } else {
            return bS[c % 3][kh];
        }
    };

    auto compute = [&](auto CC) {
        constexpr int c = decltype(CC)::value;
        const char* bp = Wbuf + (c % 5) * 8192 + ln * 64;
        #pragma unroll
        for (int kh = 0; kh < 2; ++kh) {
            bf16x8 b = getB(CC, kh);
            #pragma unroll
            for (int nt = 0; nt < 4; ++nt) {
                bf16x8 a = *(const bf16x8*)(bp + nt * 2048
                            + (((kh * 2 + hi) ^ sxA) << 4));
                acc[nt] = __builtin_amdgcn_mfma_f32_32x32x16_bf16(a, b, acc[nt], 0, 0, 0);
            }
        }
    };

    auto epiH = [&](const float* bias) {
        #pragma unroll
        for (int nt = 0; nt < 4; ++nt) {
            #pragma unroll
            for (int rq = 0; rq < 4; ++rq) {
                f32x4 bv = *(const f32x4*)(bias + nt * 32 + rq * 8 + hi * 4);
                unsigned short h[4];
                #pragma unroll
                for (int j = 0; j < 4; ++j)
                    h[j] = bfr(fmaxf(acc[nt][rq * 4 + j] + bv[j], 0.f));
                char* p = Hb + w * 8192 + ln * 256
                        + (((nt * 4 + rq) ^ sxH) << 4) + hi * 8;
                unsigned lo = (unsigned)h[0] | ((unsigned)h[1] << 16);
                unsigned hx = (unsigned)h[2] | ((unsigned)h[3] << 16);
                *(unsigned long long*)p =
                    (unsigned long long)lo | ((unsigned long long)hx << 32);
            }
            acc[nt] = fz;
        }
    };

#define PITER(C, VM)                                                          \
    {                                                                         \
        if constexpr ((C) + 3 < NCH) stageW((C) + 3);                         \
        __builtin_amdgcn_sched_barrier(0);                                    \
        if constexpr ((C) + 2 < NK1) {                                        \
            if constexpr (MODE == 0 && (C) + 2 >= 8)                          \
                loadBF(ic<(C) + 2>{}, fS[((C) + 2) % 3]);                     \
            else                                                              \
                loadBB(ic<(C) + 2>{}, bS[((C) + 2) % 3]);                     \
        }                                                                     \
        __builtin_amdgcn_sched_barrier(0);                                    \
        asm volatile("s_waitcnt vmcnt(" #VM ")" ::: "memory");                \
        __builtin_amdgcn_sched_barrier(0);                                    \
        __builtin_amdgcn_s_barrier();                                         \
        __builtin_amdgcn_sched_barrier(0);                                    \
        compute(ic<(C)>{});                                                   \
    }

    // prologue: S0,B0,S1,B1,S2 (order pinned) -> FIFO depth 10
    stageW(0);
    __builtin_amdgcn_sched_barrier(0);
    loadBB(ic<0>{}, bS[0]);
    __builtin_amdgcn_sched_barrier(0);
    stageW(1);
    __builtin_amdgcn_sched_barrier(0);
    loadBB(ic<1>{}, bS[1]);
    __builtin_amdgcn_sched_barrier(0);
    stageW(2);
    __builtin_amdgcn_sched_barrier(0);

    // Exact stage-only vmcnt: VM_c = ops_issued_after_stage(c) at wait point.
    if constexpr (MODE == 0) {
        PITER(0, 12)  PITER(1, 12)  PITER(2, 12)  PITER(3, 14)
        PITER(4, 14)  PITER(5, 14)  PITER(6, 14)  PITER(7, 14)
        PITER(8, 14)  PITER(9, 14)  PITER(10, 12) PITER(11, 10)
        epiH(b1);
        PITER(12, 8)  PITER(13, 6)  PITER(14, 6)  PITER(15, 6)
        epiH(b2);
        PITER(16, 6)  PITER(17, 4)  PITER(18, 2)  PITER(19, 0)
    } else {
        PITER(0, 12)  PITER(1, 12)  PITER(2, 12)  PITER(3, 14)
        PITER(4, 14)  PITER(5, 14)  PITER(6, 12)  PITER(7, 10)
        epiH(b1);
        PITER(8, 8)   PITER(9, 6)   PITER(10, 6)  PITER(11, 6)
        epiH(b2);
        PITER(12, 6)  PITER(13, 4)  PITER(14, 2)  PITER(15, 0)
    }
#undef PITER

    // ================= bias3 + LayerNorm + residual (+ ybuf) =================
    float vsum = 0.f, vsq = 0.f;
    #pragma unroll
    for (int nt = 0; nt < 4; ++nt) {
        #pragma unroll
        for (int rq = 0; rq < 4; ++rq) {
            f32x4 bv = *(const f32x4*)(b3 + nt * 32 + rq * 8 + hi * 4);
            #pragma unroll
            for (int j = 0; j < 4; ++j) {
                float v = acc[nt][rq * 4 + j] + bv[j];
                acc[nt][rq * 4 + j] = v;
                vsum += v; vsq += v * v;
            }
        }
    }
    vsum += __shfl_xor(vsum, 32);
    vsq  += __shfl_xor(vsq, 32);
    const float mu = vsum * (1.f / DD);
    const float rs = rsqrtf(vsq * (1.f / DD) - mu * mu + LN_EPS);

    if (gm < NROWS) {
        const float* resid = ((MODE == 0) ? edgef : nodef) + (size_t)gm * DD;
        #pragma unroll
        for (int nt = 0; nt < 4; ++nt) {
            #pragma unroll
            for (int rq = 0; rq < 4; ++rq) {
                const int n0 = nt * 32 + rq * 8 + hi * 4;
                f32x4 gv = *(const f32x4*)(gamma + n0);
                f32x4 bv = *(const f32x4*)(beta + n0);
                f32x4 rv = *(const f32x4*)(resid + n0);
                float y[4];
                f32x4 o;
                #pragma unroll
                for (int j = 0; j < 4; ++j) {
                    y[j] = (acc[nt][rq * 4 + j] - mu) * rs * gv[j] + bv[j];
                    o[j] = y[j] + rv[j];
                }
                *(f32x4*)(outp + (size_t)gm * DD + n0) = o;
                if (MODE == 0) {
                    unsigned long long pkd =
                        (unsigned long long)pk2(y[0], y[1])
                      | ((unsigned long long)pk2(y[2], y[3]) << 32);
                    *(unsigned long long*)((char*)ybuf + (size_t)prow * 256 + n0 * 2) = pkd;
                }
            }
        }
    }
}

extern "C" void kernel_launch(void* const* d_in, const int* in_sizes, int n_in,
                              void* d_out, int out_size, void* d_ws, size_t ws_size,
                              hipStream_t stream) {
    const float* nodef = (const float*)d_in[0];
    const float* edgef = (const float*)d_in[1];
    const int* senders   = (const int*)d_in[2];
    const int* receivers = (const int*)d_in[3];
    const float* We1 = (const float*)d_in[4],  *be1 = (const float*)d_in[5];
    const float* We2 = (const float*)d_in[6],  *be2 = (const float*)d_in[7];
    const float* We3 = (const float*)d_in[8],  *be3 = (const float*)d_in[9];
    const float* ge  = (const float*)d_in[10], *bege = (const float*)d_in[11];
    const float* Wn1 = (const float*)d_in[12], *bn1 = (const float*)d_in[13];
    const float* Wn2 = (const float*)d_in[14], *bn2 = (const float*)d_in[15];
    const float* Wn3 = (const float*)d_in[16], *bn3 = (const float*)d_in[17];
    const float* gn  = (const float*)d_in[18], *begn = (const float*)d_in[19];

    float* out_node = (float*)d_out;
    float* out_edge = (float*)d_out + (size_t)NNODES * DD;

    char* ws = (char*)d_ws;
    size_t o = 0;
    unsigned short* aggb = (unsigned short*)(ws + o); o += (size_t)NNODES * 256;
    unsigned* ybuf = (unsigned*)(ws + o);             o += (size_t)NEDGES * 256;
    unsigned short* nodb = (unsigned short*)(ws + o); o += (size_t)NNODES * 256;
    char* img_e = ws + o;           o += 20 * 8192;
    char* img_n = ws + o;           o += 16 * 8192;
    int* cnt    = (int*)(ws + o);   o += NNODES * 4;
    int* cursor = (int*)(ws + o);   o += NNODES * 4;
    int* off    = (int*)(ws + o);   o += (NNODES + 4) * 4;
    int* part   = (int*)(ws + o);   o += NTH * 4;
    int* perm   = (int*)(ws + o);   o += NEDGES * 4;

    hipMemsetAsync(cnt, 0, NNODES * 4, stream);
    cvt_histo<<<1024, NTH, 0, stream>>>(nodef, receivers, (uint4*)nodb, cnt);
    build_wimg<<<72, NTH, 0, stream>>>(We1, We2, We3, Wn1, Wn2, Wn3, img_e, img_n);
    csr_scan1<<<NTH, NTH, 0, stream>>>(cnt, part);
    csr_scan2<<<1, NTH, 0, stream>>>(cnt, part, off, cursor);
    csr_fill<<<(NEDGES + NTH - 1) / NTH, NTH, 0, stream>>>(receivers, cursor, perm);

    mgn_mfma<0><<<dim3((NEDGES + 127) / 128), dim3(NTH), 0, stream>>>(
        nodef, edgef, nodb, senders, receivers, perm, img_e,
        be1, be2, be3, ge, bege, aggb, ybuf, out_edge);

    aggregate<<<(NNODES + 3) / 4, NTH, 0, stream>>>(ybuf, off, (unsigned*)aggb);

    mgn_mfma<1><<<dim3((NNODES + 127) / 128), dim3(NTH), 0, stream>>>(
        nodef, edgef, nodb, senders, receivers, perm, img_n,
        bn1, bn2, bn3, gn, begn, aggb, ybuf, out_node);
}

// Round 12
// 311.850 us; speedup vs baseline: 1.1444x; 1.0144x over previous
//
#include <hip/hip_runtime.h>

#define NNODES 50000
#define NEDGES 200000
#define DD 128
#define LN_EPS 1e-5f
#define NTH 256

typedef __attribute__((ext_vector_type(8))) short bf16x8;
typedef __attribute__((ext_vector_type(4))) float f32x4;
typedef __attribute__((ext_vector_type(16))) float f32x16;

template<int N> struct ic { static constexpr int value = N; };

__device__ __forceinline__ unsigned short bfr(float f) {
    union { float f; unsigned u; } v; v.f = f;
    return (unsigned short)((v.u + 0x7fffu + ((v.u >> 16) & 1u)) >> 16);
}
__device__ __forceinline__ unsigned pk2(float a, float b) {
    return (unsigned)bfr(a) | ((unsigned)bfr(b) << 16);
}
__device__ __forceinline__ void gload_lds16(const void* g, void* l) {
    __builtin_amdgcn_global_load_lds(
        (const __attribute__((address_space(1))) void*)g,
        (__attribute__((address_space(3))) void*)l, 16, 0, 0);
}

// ---------------------------------------------------------------------------
// Fused pre-pass: blocks [0,72)  -> weight image builder (r6-proven layout)
//                 blocks [72, +1024) -> nodef bf16 mirror + receiver histogram
// Weight image per k32 chunk c (8 KB): granule(nt, n32, ks):
//   byte = c*8192 + nt*2048 + n32*64 + ((ks ^ ((n32 + (n32>>2)) & 3)) << 4)
//   content: Wt[n = nt*32+n32][k = c*32 + ks*8 + e], e=0..7 (bf16)
// ---------------------------------------------------------------------------
__global__ __launch_bounds__(NTH)
void prepass(const float* __restrict__ We1, const float* __restrict__ We2,
             const float* __restrict__ We3, const float* __restrict__ Wn1,
             const float* __restrict__ Wn2, const float* __restrict__ Wn3,
             char* __restrict__ img_e, char* __restrict__ img_n,
             const float* __restrict__ nodef, const int* __restrict__ recv,
             uint4* __restrict__ nodb, int* __restrict__ cnt) {
    if (blockIdx.x < 72) {
        int tid = blockIdx.x * NTH + threadIdx.x;
        const float* W; char* dst; int q;
        if      (tid <  6144) { W = We1; dst = img_e;             q = tid;         }
        else if (tid <  8192) { W = We2; dst = img_e + 12 * 8192; q = tid - 6144;  }
        else if (tid < 10240) { W = We3; dst = img_e + 16 * 8192; q = tid - 8192;  }
        else if (tid < 14336) { W = Wn1; dst = img_n;             q = tid - 10240; }
        else if (tid < 16384) { W = Wn2; dst = img_n + 8 * 8192;  q = tid - 14336; }
        else if (tid < 18432) { W = Wn3; dst = img_n + 12 * 8192; q = tid - 16384; }
        else return;
        int c = q >> 9, rem = q & 511;
        int nt = rem >> 7, r2 = rem & 127, n32 = r2 >> 2, ks = r2 & 3;
        int n = nt * 32 + n32;
        int sx = (n32 + (n32 >> 2)) & 3;
        int k0 = c * 32 + ks * 8;
        unsigned short o[8];
        #pragma unroll
        for (int e = 0; e < 8; ++e)
            o[e] = bfr(W[(size_t)(k0 + e) * DD + n]);
        uint4 val;
        val.x = (unsigned)o[0] | ((unsigned)o[1] << 16);
        val.y = (unsigned)o[2] | ((unsigned)o[3] << 16);
        val.z = (unsigned)o[4] | ((unsigned)o[5] << 16);
        val.w = (unsigned)o[6] | ((unsigned)o[7] << 16);
        *(uint4*)(dst + (size_t)c * 8192 + nt * 2048 + n32 * 64 + ((ks ^ sx) << 4)) = val;
    } else {
        const int b = blockIdx.x - 72;
        const int tid0 = b * NTH + threadIdx.x;
        if (tid0 < NEDGES) atomicAdd(&cnt[recv[tid0]], 1);
        const int NG = NNODES * 16;
        for (int g = tid0; g < NG; g += 1024 * NTH) {
            f32x4 a = ((const f32x4*)nodef)[g * 2];
            f32x4 bb = ((const f32x4*)nodef)[g * 2 + 1];
            uint4 o;
            o.x = pk2(a[0], a[1]); o.y = pk2(a[2], a[3]);
            o.z = pk2(bb[0], bb[1]); o.w = pk2(bb[2], bb[3]);
            nodb[g] = o;
        }
    }
}

// ---------------------------------------------------------------------------
// CSR: 2-level scan + fill (stores perm[e] = CSR position of edge e)
// ---------------------------------------------------------------------------
__global__ __launch_bounds__(NTH)
void csr_scan1(const int* __restrict__ cnt, int* __restrict__ part) {
    __shared__ int red[NTH];
    const int b = blockIdx.x, t = threadIdx.x;
    const int base = b * 196;
    int s = 0;
    for (int i = t; i < 196; i += NTH) {
        int idx = base + i;
        if (idx < NNODES) s += cnt[idx];
    }
    red[t] = s;
    __syncthreads();
    for (int d = NTH / 2; d > 0; d >>= 1) {
        if (t < d) red[t] += red[t + d];
        __syncthreads();
    }
    if (t == 0) part[b] = red[0];
}

__global__ __launch_bounds__(NTH)
void csr_scan2(const int* __restrict__ cnt, const int* __restrict__ part,
               int* __restrict__ off, int* __restrict__ cursor) {
    __shared__ int sp[NTH];
    const int t = threadIdx.x;
    sp[t] = part[t];
    __syncthreads();
    for (int d = 1; d < NTH; d <<= 1) {
        int v = (t >= d) ? sp[t - d] : 0;
        __syncthreads();
        sp[t] += v;
        __syncthreads();
    }
    int run = (t == 0) ? 0 : sp[t - 1];
    const int base = t * 196;
    for (int i = 0; i < 196; ++i) {
        int idx = base + i;
        if (idx < NNODES) { off[idx] = run; cursor[idx] = run; run += cnt[idx]; }
    }
    if (t == NTH - 1) off[NNODES] = NEDGES;
}

__global__ void csr_fill(const int* __restrict__ recv, int* __restrict__ cursor,
                         int* __restrict__ perm) {
    int e = blockIdx.x * NTH + threadIdx.x;
    if (e < NEDGES) {
        int p = atomicAdd(&cursor[recv[e]], 1);
        perm[e] = p;
    }
}

// ---------------------------------------------------------------------------
// Aggregate (bf16): ybuf is CSR-ordered -> pure streaming reads.
// ---------------------------------------------------------------------------
__global__ __launch_bounds__(NTH)
void aggregate(const unsigned* __restrict__ ybuf,
               const int* __restrict__ off,
               unsigned* __restrict__ aggb) {
    const int n = blockIdx.x * 4 + (threadIdx.x >> 6);
    const int l = threadIdx.x & 63;
    if (n >= NNODES) return;
    const int j0 = off[n], j1 = off[n + 1];
    float sx = 0.f, sy = 0.f;
    int j = j0;
    for (; j + 4 <= j1; j += 4) {
        unsigned v0 = ybuf[(size_t)j * 64 + l];
        unsigned v1 = ybuf[(size_t)(j + 1) * 64 + l];
        unsigned v2 = ybuf[(size_t)(j + 2) * 64 + l];
        unsigned v3 = ybuf[(size_t)(j + 3) * 64 + l];
        sx += __uint_as_float(v0 << 16) + __uint_as_float(v1 << 16)
            + __uint_as_float(v2 << 16) + __uint_as_float(v3 << 16);
        sy += __uint_as_float(v0 & 0xffff0000u) + __uint_as_float(v1 & 0xffff0000u)
            + __uint_as_float(v2 & 0xffff0000u) + __uint_as_float(v3 & 0xffff0000u);
    }
    for (; j < j1; ++j) {
        unsigned v = ybuf[(size_t)j * 64 + l];
        sx += __uint_as_float(v << 16);
        sy += __uint_as_float(v & 0xffff0000u);
    }
    aggb[(size_t)n * 64 + l] = pk2(sx, sy);
}

// ---------------------------------------------------------------------------
// Fused MLP, 32x32x16 MFMA.  Two-chunk (BK=64) macro-iterations:
// one s_barrier + one counted vmcnt per TWO k32 chunks (sync events halved).
// 6 Wbuf buffers, barrier-FIRST ordering (stage of buf[(2m-2)%6] is issued
// only after barrier(m), i.e., after all waves finished compute(m-1) -> safe).
// B: 4-slot register rings (bf16 nodb/aggb; fp32 edgef stream on edge 8..11).
// H1/H2: wave-private swizzled LDS (r6-proven epiH/loadBH).
// ---------------------------------------------------------------------------
template<int MODE>
__global__ __launch_bounds__(NTH, 2)
void mgn_mfma(const float* __restrict__ nodef, const float* __restrict__ edgef,
              const unsigned short* __restrict__ nodb,
              const int* __restrict__ senders, const int* __restrict__ receivers,
              const int* __restrict__ perm,
              const char* __restrict__ img,
              const float* __restrict__ b1, const float* __restrict__ b2,
              const float* __restrict__ b3,
              const float* __restrict__ gamma, const float* __restrict__ beta,
              const unsigned short* __restrict__ aggb, unsigned* __restrict__ ybuf,
              float* __restrict__ outp)
{
    __shared__ char Wbuf[6 * 8192];   // 6 rotating k32 weight chunks (3 pairs)
    __shared__ char Hb[4 * 8192];     // per-wave 32 rows x 128 k bf16, swizzled

    const int t  = threadIdx.x;
    const int w  = t >> 6;
    const int l  = t & 63;
    const int ln = l & 31;
    const int hi = l >> 5;
    const int row0 = blockIdx.x * 128;
    const int gm = row0 + w * 32 + ln;
    constexpr int NROWS = (MODE == 0) ? NEDGES : NNODES;
    constexpr int NK1   = (MODE == 0) ? 12 : 8;
    constexpr int NCH   = NK1 + 8;
    const int gmc = gm < NROWS ? gm : NROWS - 1;
    const int sxA = (ln + (ln >> 2)) & 3;
    const int sxH = ln & 15;

    int srow = 0, rrow = 0, prow = 0;
    if (MODE == 0) { srow = senders[gmc]; rrow = receivers[gmc]; prow = perm[gmc]; }

    const f32x16 fz = {0.f,0.f,0.f,0.f,0.f,0.f,0.f,0.f,
                       0.f,0.f,0.f,0.f,0.f,0.f,0.f,0.f};
    f32x16 acc[4];
    #pragma unroll
    for (int nt = 0; nt < 4; ++nt) acc[nt] = fz;

    bf16x8 bS[4][2];   // bf16 B ring (4 chunk slots)
    f32x4  fS[4][4];   // fp32 B ring (edge chunks 8..11)

    auto stageW = [&](int c) {
        const char* src = img + (size_t)c * 8192 + t * 16;
        char* dstl = Wbuf + (c % 6) * 8192 + t * 16;
        gload_lds16(src, dstl);
        gload_lds16(src + 4096, dstl + 4096);
    };

    auto loadBB = [&](auto CC, bf16x8* dst) {
        constexpr int c = decltype(CC)::value;
        const unsigned short* base;
        if constexpr (MODE == 0) {
            base = (c < 4) ? nodb + (size_t)srow * DD : nodb + (size_t)rrow * DD;
        } else {
            base = (c < 4) ? nodb + (size_t)gmc * DD : aggb + (size_t)gmc * DD;
        }
        const char* p = (const char*)base + (c & 3) * 64 + hi * 16;
        dst[0] = *(const bf16x8*)p;
        dst[1] = *(const bf16x8*)(p + 32);
    };

    auto loadBF = [&](auto CC, f32x4* dst) {
        constexpr int c = decltype(CC)::value;
        const float* p = edgef + (size_t)gmc * DD + (c & 3) * 32 + hi * 8;
        dst[0] = *(const f32x4*)p;
        dst[1] = *(const f32x4*)(p + 4);
        dst[2] = *(const f32x4*)(p + 16);
        dst[3] = *(const f32x4*)(p + 20);
    };

    auto cvtB = [&](const f32x4* br) {
        union { unsigned u[4]; bf16x8 v; } r;
        r.u[0] = pk2(br[0][0], br[0][1]);
        r.u[1] = pk2(br[0][2], br[0][3]);
        r.u[2] = pk2(br[1][0], br[1][1]);
        r.u[3] = pk2(br[1][2], br[1][3]);
        return r.v;
    };

    auto loadBH = [&](int ks, int kh) {
        const char* p = Hb + w * 8192 + ln * 256
                      + (((ks * 4 + kh * 2 + hi) ^ sxH) << 4);
        return *(const bf16x8*)p;
    };

    auto getB = [&](auto CC, int kh) -> bf16x8 {
        constexpr int c = decltype(CC)::value;
        if constexpr (c >= NK1) {
            return loadBH((c - NK1) & 3, kh);
        } else if constexpr (MODE == 0 && c >= 8) {
            return cvtB(&fS[c & 3][kh * 2]);
        } else {
            return bS[c & 3][kh];
        }
    };

    auto compute = [&](auto CC) {
        constexpr int c = decltype(CC)::value;
        const char* bp = Wbuf + (c % 6) * 8192 + ln * 64;
        #pragma unroll
        for (int kh = 0; kh < 2; ++kh) {
            bf16x8 b = getB(CC, kh);
            #pragma unroll
            for (int nt = 0; nt < 4; ++nt) {
                bf16x8 a = *(const bf16x8*)(bp + nt * 2048
                            + (((kh * 2 + hi) ^ sxA) << 4));
                acc[nt] = __builtin_amdgcn_mfma_f32_32x32x16_bf16(a, b, acc[nt], 0, 0, 0);
            }
        }
    };

    auto epiH = [&](const float* bias) {
        #pragma unroll
        for (int nt = 0; nt < 4; ++nt) {
            #pragma unroll
            for (int rq = 0; rq < 4; ++rq) {
                f32x4 bv = *(const f32x4*)(bias + nt * 32 + rq * 8 + hi * 4);
                unsigned short h[4];
                #pragma unroll
                for (int j = 0; j < 4; ++j)
                    h[j] = bfr(fmaxf(acc[nt][rq * 4 + j] + bv[j], 0.f));
                char* p = Hb + w * 8192 + ln * 256
                        + (((nt * 4 + rq) ^ sxH) << 4) + hi * 8;
                unsigned lo = (unsigned)h[0] | ((unsigned)h[1] << 16);
                unsigned hx = (unsigned)h[2] | ((unsigned)h[3] << 16);
                *(unsigned long long*)p =
                    (unsigned long long)lo | ((unsigned long long)hx << 32);
            }
            acc[nt] = fz;
        }
    };

    // loadB dispatcher for chunk c (bf16 vs fp32-edgef)
    auto loadB = [&](auto CC) {
        constexpr int c = decltype(CC)::value;
        if constexpr (c < NK1) {
            if constexpr (MODE == 0 && c >= 8) loadBF(CC, fS[c & 3]);
            else                               loadBB(CC, bS[c & 3]);
        }
    };

// Macro-iter M: chunks (2M, 2M+1). barrier -> stage pair (2M+4,2M+5) ->
// B pair (2M+2,2M+3) -> exact vmcnt (stage S(2M+1) retired) -> compute pair.
#define PITER2(M, VM)                                                         \
    {                                                                         \
        __builtin_amdgcn_s_barrier();                                         \
        __builtin_amdgcn_sched_barrier(0);                                    \
        if constexpr (2*(M) + 4 < NCH) stageW(2*(M) + 4);                     \
        if constexpr (2*(M) + 5 < NCH) stageW(2*(M) + 5);                     \
        __builtin_amdgcn_sched_barrier(0);                                    \
        loadB(ic<2*(M) + 2>{});                                               \
        loadB(ic<2*(M) + 3>{});                                               \
        __builtin_amdgcn_sched_barrier(0);                                    \
        asm volatile("s_waitcnt vmcnt(" #VM ")" ::: "memory");                \
        __builtin_amdgcn_sched_barrier(0);                                    \
        compute(ic<2*(M)>{});                                                 \
        compute(ic<2*(M) + 1>{});                                             \
    }

    // prologue: S0,S1,S2,S3 then B0,B1 (order pinned)
    stageW(0);
    __builtin_amdgcn_sched_barrier(0);
    stageW(1);
    __builtin_amdgcn_sched_barrier(0);
    stageW(2);
    __builtin_amdgcn_sched_barrier(0);
    stageW(3);
    __builtin_amdgcn_sched_barrier(0);
    loadB(ic<0>{});
    loadB(ic<1>{});
    __builtin_amdgcn_sched_barrier(0);

    if constexpr (MODE == 0) {
        PITER2(0, 16)  PITER2(1, 20)  PITER2(2, 20)  PITER2(3, 24)
        PITER2(4, 28)  PITER2(5, 24)
        epiH(b1);
        PITER2(6, 16)  PITER2(7, 8)
        epiH(b2);
        PITER2(8, 4)   PITER2(9, 0)
    } else {
        PITER2(0, 16)  PITER2(1, 20)  PITER2(2, 20)  PITER2(3, 16)
        epiH(b1);
        PITER2(4, 12)  PITER2(5, 8)
        epiH(b2);
        PITER2(6, 4)   PITER2(7, 0)
    }
#undef PITER2

    // ================= bias3 + LayerNorm + residual (+ ybuf) =================
    float vsum = 0.f, vsq = 0.f;
    #pragma unroll
    for (int nt = 0; nt < 4; ++nt) {
        #pragma unroll
        for (int rq = 0; rq < 4; ++rq) {
            f32x4 bv = *(const f32x4*)(b3 + nt * 32 + rq * 8 + hi * 4);
            #pragma unroll
            for (int j = 0; j < 4; ++j) {
                float v = acc[nt][rq * 4 + j] + bv[j];
                acc[nt][rq * 4 + j] = v;
                vsum += v; vsq += v * v;
            }
        }
    }
    vsum += __shfl_xor(vsum, 32);
    vsq  += __shfl_xor(vsq, 32);
    const float mu = vsum * (1.f / DD);
    const float rs = rsqrtf(vsq * (1.f / DD) - mu * mu + LN_EPS);

    if (gm < NROWS) {
        const float* resid = ((MODE == 0) ? edgef : nodef) + (size_t)gm * DD;
        #pragma unroll
        for (int nt = 0; nt < 4; ++nt) {
            #pragma unroll
            for (int rq = 0; rq < 4; ++rq) {
                const int n0 = nt * 32 + rq * 8 + hi * 4;
                f32x4 gv = *(const f32x4*)(gamma + n0);
                f32x4 bv = *(const f32x4*)(beta + n0);
                f32x4 rv = *(const f32x4*)(resid + n0);
                float y[4];
                f32x4 o;
                #pragma unroll
                for (int j = 0; j < 4; ++j) {
                    y[j] = (acc[nt][rq * 4 + j] - mu) * rs * gv[j] + bv[j];
                    o[j] = y[j] + rv[j];
                }
                *(f32x4*)(outp + (size_t)gm * DD + n0) = o;
                if (MODE == 0) {
                    unsigned long long pkd =
                        (unsigned long long)pk2(y[0], y[1])
                      | ((unsigned long long)pk2(y[2], y[3]) << 32);
                    *(unsigned long long*)((char*)ybuf + (size_t)prow * 256 + n0 * 2) = pkd;
                }
            }
        }
    }
}

extern "C" void kernel_launch(void* const* d_in, const int* in_sizes, int n_in,
                              void* d_out, int out_size, void* d_ws, size_t ws_size,
                              hipStream_t stream) {
    const float* nodef = (const float*)d_in[0];
    const float* edgef = (const float*)d_in[1];
    const int* senders   = (const int*)d_in[2];
    const int* receivers = (const int*)d_in[3];
    const float* We1 = (const float*)d_in[4],  *be1 = (const float*)d_in[5];
    const float* We2 = (const float*)d_in[6],  *be2 = (const float*)d_in[7];
    const float* We3 = (const float*)d_in[8],  *be3 = (const float*)d_in[9];
    const float* ge  = (const float*)d_in[10], *bege = (const float*)d_in[11];
    const float* Wn1 = (const float*)d_in[12], *bn1 = (const float*)d_in[13];
    const float* Wn2 = (const float*)d_in[14], *bn2 = (const float*)d_in[15];
    const float* Wn3 = (const float*)d_in[16], *bn3 = (const float*)d_in[17];
    const float* gn  = (const float*)d_in[18], *begn = (const float*)d_in[19];

    float* out_node = (float*)d_out;
    float* out_edge = (float*)d_out + (size_t)NNODES * DD;

    char* ws = (char*)d_ws;
    size_t o = 0;
    unsigned short* aggb = (unsigned short*)(ws + o); o += (size_t)NNODES * 256;
    unsigned* ybuf = (unsigned*)(ws + o);             o += (size_t)NEDGES * 256;
    unsigned short* nodb = (unsigned short*)(ws + o); o += (size_t)NNODES * 256;
    char* img_e = ws + o;           o += 20 * 8192;
    char* img_n = ws + o;           o += 16 * 8192;
    int* cnt    = (int*)(ws + o);   o += NNODES * 4;
    int* cursor = (int*)(ws + o);   o += NNODES * 4;
    int* off    = (int*)(ws + o);   o += (NNODES + 4) * 4;
    int* part   = (int*)(ws + o);   o += NTH * 4;
    int* perm   = (int*)(ws + o);   o += NEDGES * 4;

    hipMemsetAsync(cnt, 0, NNODES * 4, stream);
    prepass<<<72 + 1024, NTH, 0, stream>>>(We1, We2, We3, Wn1, Wn2, Wn3,
                                           img_e, img_n,
                                           nodef, receivers, (uint4*)nodb, cnt);
    csr_scan1<<<NTH, NTH, 0, stream>>>(cnt, part);
    csr_scan2<<<1, NTH, 0, stream>>>(cnt, part, off, cursor);
    csr_fill<<<(NEDGES + NTH - 1) / NTH, NTH, 0, stream>>>(receivers, cursor, perm);

    mgn_mfma<0><<<dim3((NEDGES + 127) / 128), dim3(NTH), 0, stream>>>(
        nodef, edgef, nodb, senders, receivers, perm, img_e,
        be1, be2, be3, ge, bege, aggb, ybuf, out_edge);

    aggregate<<<(NNODES + 3) / 4, NTH, 0, stream>>>(ybuf, off, (unsigned*)aggb);

    mgn_mfma<1><<<dim3((NNODES + 127) / 128), dim3(NTH), 0, stream>>>(
        nodef, edgef, nodb, senders, receivers, perm, img_n,
        bn1, bn2, bn3, gn, begn, aggb, ybuf, out_node);
}